// Round 3
// baseline (567.626 us; speedup 1.0000x reference)
//
#include <hip/hip_runtime.h>
#include <hip/hip_bf16.h>
#include <math.h>
#include <stdint.h>

typedef unsigned short u16;
typedef unsigned int u32;
typedef __attribute__((ext_vector_type(8))) short short8;   // 8 bf16 = 4 VGPRs (MFMA A/B frag)
typedef __attribute__((ext_vector_type(4))) float f32x4;    // MFMA C/D frag

__device__ __forceinline__ float b2f(u16 u) {
  union { u32 i; float f; } v; v.i = ((u32)u) << 16; return v.f;
}
__device__ __forceinline__ u16 f2b(float f) {
  union { float f; u32 i; } v; v.f = f;
  return (u16)((v.i + 0x7FFFu + ((v.i >> 16) & 1u)) >> 16);  // RNE
}

// async global->LDS DMA, 16B per lane; LDS dest = wave-uniform base + lane*16B
__device__ __forceinline__ void gload_lds16(const u16* g, u16* l) {
  __builtin_amdgcn_global_load_lds((const __attribute__((address_space(1))) void*)g,
                                   (__attribute__((address_space(3))) void*)l, 16, 0, 0);
}

#define LD8(p) (*(const short8*)(p))
#define MFMA_BF16 __builtin_amdgcn_mfma_f32_16x16x32_bf16

// ---------------- fused transpose+convert: fp32 (K x N) -> bf16 (N x K) ----------------
__global__ __launch_bounds__(256) void transpose_k(const float* __restrict__ in,
                                                   u16* __restrict__ out, int K, int N) {
  __shared__ u16 tile[32][33];
  int n0 = blockIdx.x * 32, k0 = blockIdx.y * 32;
  int tx = threadIdx.x & 31, ty = threadIdx.x >> 5;
  #pragma unroll
  for (int i = ty; i < 32; i += 8)
    tile[i][tx] = f2b(in[(size_t)(k0 + i) * N + n0 + tx]);
  __syncthreads();
  #pragma unroll
  for (int i = ty; i < 32; i += 8)
    out[(size_t)(n0 + i) * K + k0 + tx] = tile[tx][i];
}

// ---------------- concat 3 x 1024 fp32 biases ----------------
__global__ __launch_bounds__(256) void cat3_k(const float* __restrict__ a, const float* __restrict__ b,
                                              const float* __restrict__ c, float* __restrict__ o) {
  int i = blockIdx.x * 256 + threadIdx.x;
  o[i] = i < 1024 ? a[i] : (i < 2048 ? b[i - 1024] : c[i - 2048]);
}

// ---------------- per-head V transpose from strided qkv: v[s][2048+h*64+d] -> vt[(bh*64+d)][s] ----------------
__global__ __launch_bounds__(256) void vtrans_k(const u16* __restrict__ qkv, u16* __restrict__ vt) {
  __shared__ u16 tile[32][33];
  int bh = blockIdx.y, b = bh >> 4, h = bh & 15;
  int s0 = (blockIdx.x & 31) * 32, d0 = (blockIdx.x >> 5) * 32;
  int tx = threadIdx.x & 31, ty = threadIdx.x >> 5;
  #pragma unroll
  for (int i = ty; i < 32; i += 8)
    tile[i][tx] = qkv[(size_t)(b * 1024 + s0 + i) * 3072 + 2048 + h * 64 + d0 + tx];
  __syncthreads();
  #pragma unroll
  for (int i = ty; i < 32; i += 8)
    vt[(size_t)(bh * 64 + d0 + i) * 1024 + s0 + tx] = tile[tx][i];
}

// ---------------- LayerNorm over D=1024, one block per row; FP32IN: x fp32 vs bf16 ----------------
template<int FP32IN>
__global__ __launch_bounds__(256) void ln_k(const void* __restrict__ xv, const float* __restrict__ g,
                                            const float* __restrict__ be, u16* __restrict__ out) {
  int row = blockIdx.x, t = threadIdx.x;
  float f0, f1, f2, f3;
  if (FP32IN) {
    const float* xr = (const float*)xv + (size_t)row * 1024;
    float4 x4 = *(const float4*)(xr + t * 4);
    f0 = x4.x; f1 = x4.y; f2 = x4.z; f3 = x4.w;
  } else {
    const u16* xr = (const u16*)xv + (size_t)row * 1024;
    ushort4 x4 = *(const ushort4*)(xr + t * 4);
    f0 = b2f(x4.x); f1 = b2f(x4.y); f2 = b2f(x4.z); f3 = b2f(x4.w);
  }
  float s = f0 + f1 + f2 + f3;
  float ss = f0 * f0 + f1 * f1 + f2 * f2 + f3 * f3;
  #pragma unroll
  for (int off = 32; off > 0; off >>= 1) { s += __shfl_down(s, off); ss += __shfl_down(ss, off); }
  __shared__ float sb[4], ssb[4];
  if ((t & 63) == 0) { sb[t >> 6] = s; ssb[t >> 6] = ss; }
  __syncthreads();
  s = sb[0] + sb[1] + sb[2] + sb[3];
  ss = ssb[0] + ssb[1] + ssb[2] + ssb[3];
  float mu = s * (1.0f / 1024.0f);
  float var = ss * (1.0f / 1024.0f) - mu * mu;
  float rstd = rsqrtf(var + 1e-5f);
  float4 gv = *(const float4*)(g + t * 4);
  float4 bv = *(const float4*)(be + t * 4);
  ushort4 o;
  o.x = f2b((f0 - mu) * rstd * gv.x + bv.x);
  o.y = f2b((f1 - mu) * rstd * gv.y + bv.y);
  o.z = f2b((f2 - mu) * rstd * gv.z + bv.z);
  o.w = f2b((f3 - mu) * rstd * gv.w + bv.w);
  *(ushort4*)(out + (size_t)row * 1024 + t * 4) = o;
}

// ---------------- GEMM: C[M,N] = act(A[M,K] @ Bt[N,K]^T + bias) (+resid), ldc-strided C --------
// 8-phase template port (learn_hip m194-m201 / T2+T3+T4+T5): BM=128 BN=256 BK=64, 8 waves (512thr),
// wave grid 2Mx4N, per-wave 64x64 out. Grid dim3(64, N/256); XCD remap as before (bijective).
// LDS: 3 buffers x (A 16KB + B 32KB) = 144KB, 1 block/CU, prefetch depth 2 K-tiles.
// Per K-tile: 4 phases {ds_read subtile || issue gloads -> barrier -> lgkmcnt(0) -> sched_barrier
// -> setprio(1) -> 8 MFMA -> setprio(0) -> barrier}. vmcnt(6) once per K-tile (6 gloads/K-tile,
// depth-1 in flight = 6). WAR-safe: buf written at group t ((t+2)%3) was last read at group t-1,
// retired (lgkmcnt0+barrier) before group t begins. Cross-wave: each wave vmcnt(6) BEFORE barrier.
// T2: 8-chunk XOR swizzle, src-permuted global addr + swizzled ds_read (LDS dest linear, rule #21).
template<int ACT, int RESID, int OUTF32>
__global__ __launch_bounds__(512) void gemm_k(const u16* __restrict__ A, const u16* __restrict__ Bt,
                                              const float* __restrict__ bias, const void* __restrict__ resid,
                                              void* __restrict__ Cv, int M, int N, int K, int ldc) {
  __shared__ u16 As[3][128 * 64];   // 48KB
  __shared__ u16 Bs[3][256 * 64];   // 96KB
  int Ny = N >> 8;
  int lin = blockIdx.y * 64 + blockIdx.x;
  int c8 = lin & 7, sblk = lin >> 3;
  int mq = sblk / Ny;
  int m0 = ((mq << 3) | c8) << 7;
  int n0 = (sblk - mq * Ny) << 8;
  int t = threadIdx.x;
  int wave = t >> 6, lane = t & 63, quad = lane >> 4, l16 = lane & 15;
  int wm = (wave >> 2) << 6;            // 0 | 64
  int wn = (wave & 3) << 6;             // 0..192
  f32x4 acc[4][4] = {};
  int lrow = lane >> 3;                 // 0..7
  int lchunk = (lane & 7) ^ lrow;       // source-permute: phys chunk = logical ^ (row&7)
  const u16* Ab = A + (size_t)(m0 + wave * 16 + lrow) * K + lchunk * 8;
  const u16* Bb = Bt + (size_t)(n0 + wave * 32 + lrow) * K + lchunk * 8;
  const int aw = wave * 16 * 64;        // wave's A slab base (elements)
  const int bw = wave * 32 * 64;        // wave's B slab base
  const int x7 = l16 & 7;
  const int rbA = (wm + l16) * 64;      // frag row bases (elements)
  const int rbB = (wn + l16) * 64;
  const int c0 = (quad ^ x7) * 8;       // kk=0 swizzled chunk byte/2 offset
  const int c1 = ((4 + quad) ^ x7) * 8; // kk=1
  const int niter = K >> 6;
  // ---- prologue: tiles 0 -> buf0, 1 -> buf1 ----
  #pragma unroll
  for (int g = 0; g < 2; g++) gload_lds16(Ab + (size_t)g * 8 * K, &As[0][aw + g * 8 * 64]);
  #pragma unroll
  for (int g = 0; g < 4; g++) gload_lds16(Bb + (size_t)g * 8 * K, &Bs[0][bw + g * 8 * 64]);
  #pragma unroll
  for (int g = 0; g < 2; g++) gload_lds16(Ab + 64 + (size_t)g * 8 * K, &As[1][aw + g * 8 * 64]);
  #pragma unroll
  for (int g = 0; g < 4; g++) gload_lds16(Bb + 64 + (size_t)g * 8 * K, &Bs[1][bw + g * 8 * 64]);
  asm volatile("s_waitcnt vmcnt(6)" ::: "memory");   // tile0 landed; tile1 in flight
  __builtin_amdgcn_s_barrier();
  __builtin_amdgcn_sched_barrier(0);
  int cur = 0;
  for (int tt = 0; tt < niter; tt++) {
    const u16* Ac = &As[cur][0];
    const u16* Bc = &Bs[cur][0];
    int wb = cur + 2; if (wb >= 3) wb -= 3;
    const bool pf = (tt + 2 < niter);
    const int kpf = (tt + 2) << 6;
    short8 a0, a1, a2, a3, b0, b1, b2, b3;
    // ---------- P0: kk=0, i=0,1 ; stage A g0,g1 of tile tt+2 ----------
    a0 = LD8(Ac + rbA + c0);
    a1 = LD8(Ac + rbA + 1024 + c0);
    b0 = LD8(Bc + rbB + c0);
    b1 = LD8(Bc + rbB + 1024 + c0);
    b2 = LD8(Bc + rbB + 2048 + c0);
    b3 = LD8(Bc + rbB + 3072 + c0);
    if (pf) {
      gload_lds16(Ab + kpf, &As[wb][aw]);
      gload_lds16(Ab + kpf + (size_t)8 * K, &As[wb][aw + 8 * 64]);
    }
    __builtin_amdgcn_s_barrier();
    asm volatile("s_waitcnt lgkmcnt(0)" ::: "memory");
    __builtin_amdgcn_sched_barrier(0);
    __builtin_amdgcn_s_setprio(1);
    acc[0][0] = MFMA_BF16(a0, b0, acc[0][0], 0, 0, 0);
    acc[0][1] = MFMA_BF16(a0, b1, acc[0][1], 0, 0, 0);
    acc[0][2] = MFMA_BF16(a0, b2, acc[0][2], 0, 0, 0);
    acc[0][3] = MFMA_BF16(a0, b3, acc[0][3], 0, 0, 0);
    acc[1][0] = MFMA_BF16(a1, b0, acc[1][0], 0, 0, 0);
    acc[1][1] = MFMA_BF16(a1, b1, acc[1][1], 0, 0, 0);
    acc[1][2] = MFMA_BF16(a1, b2, acc[1][2], 0, 0, 0);
    acc[1][3] = MFMA_BF16(a1, b3, acc[1][3], 0, 0, 0);
    __builtin_amdgcn_s_setprio(0);
    __builtin_amdgcn_s_barrier();
    __builtin_amdgcn_sched_barrier(0);
    // ---------- P1: kk=0, i=2,3 ; stage B g0,g1 ----------
    a2 = LD8(Ac + rbA + 2048 + c0);
    a3 = LD8(Ac + rbA + 3072 + c0);
    if (pf) {
      gload_lds16(Bb + kpf, &Bs[wb][bw]);
      gload_lds16(Bb + kpf + (size_t)8 * K, &Bs[wb][bw + 8 * 64]);
    }
    __builtin_amdgcn_s_barrier();
    asm volatile("s_waitcnt lgkmcnt(0)" ::: "memory");
    __builtin_amdgcn_sched_barrier(0);
    __builtin_amdgcn_s_setprio(1);
    acc[2][0] = MFMA_BF16(a2, b0, acc[2][0], 0, 0, 0);
    acc[2][1] = MFMA_BF16(a2, b1, acc[2][1], 0, 0, 0);
    acc[2][2] = MFMA_BF16(a2, b2, acc[2][2], 0, 0, 0);
    acc[2][3] = MFMA_BF16(a2, b3, acc[2][3], 0, 0, 0);
    acc[3][0] = MFMA_BF16(a3, b0, acc[3][0], 0, 0, 0);
    acc[3][1] = MFMA_BF16(a3, b1, acc[3][1], 0, 0, 0);
    acc[3][2] = MFMA_BF16(a3, b2, acc[3][2], 0, 0, 0);
    acc[3][3] = MFMA_BF16(a3, b3, acc[3][3], 0, 0, 0);
    __builtin_amdgcn_s_setprio(0);
    __builtin_amdgcn_s_barrier();
    __builtin_amdgcn_sched_barrier(0);
    // ---------- P2: kk=1, i=0,1 ; stage B g2,g3 ----------
    a0 = LD8(Ac + rbA + c1);
    a1 = LD8(Ac + rbA + 1024 + c1);
    b0 = LD8(Bc + rbB + c1);
    b1 = LD8(Bc + rbB + 1024 + c1);
    b2 = LD8(Bc + rbB + 2048 + c1);
    b3 = LD8(Bc + rbB + 3072 + c1);
    if (pf) {
      gload_lds16(Bb + kpf + (size_t)16 * K, &Bs[wb][bw + 16 * 64]);
      gload_lds16(Bb + kpf + (size_t)24 * K, &Bs[wb][bw + 24 * 64]);
    }
    __builtin_amdgcn_s_barrier();
    asm volatile("s_waitcnt lgkmcnt(0)" ::: "memory");
    __builtin_amdgcn_sched_barrier(0);
    __builtin_amdgcn_s_setprio(1);
    acc[0][0] = MFMA_BF16(a0, b0, acc[0][0], 0, 0, 0);
    acc[0][1] = MFMA_BF16(a0, b1, acc[0][1], 0, 0, 0);
    acc[0][2] = MFMA_BF16(a0, b2, acc[0][2], 0, 0, 0);
    acc[0][3] = MFMA_BF16(a0, b3, acc[0][3], 0, 0, 0);
    acc[1][0] = MFMA_BF16(a1, b0, acc[1][0], 0, 0, 0);
    acc[1][1] = MFMA_BF16(a1, b1, acc[1][1], 0, 0, 0);
    acc[1][2] = MFMA_BF16(a1, b2, acc[1][2], 0, 0, 0);
    acc[1][3] = MFMA_BF16(a1, b3, acc[1][3], 0, 0, 0);
    __builtin_amdgcn_s_setprio(0);
    __builtin_amdgcn_s_barrier();
    __builtin_amdgcn_sched_barrier(0);
    // ---------- P3: kk=1, i=2,3 ; no stage; K-tile-end vmcnt ----------
    a2 = LD8(Ac + rbA + 2048 + c1);
    a3 = LD8(Ac + rbA + 3072 + c1);
    __builtin_amdgcn_s_barrier();
    asm volatile("s_waitcnt lgkmcnt(0)" ::: "memory");
    __builtin_amdgcn_sched_barrier(0);
    __builtin_amdgcn_s_setprio(1);
    acc[2][0] = MFMA_BF16(a2, b0, acc[2][0], 0, 0, 0);
    acc[2][1] = MFMA_BF16(a2, b1, acc[2][1], 0, 0, 0);
    acc[2][2] = MFMA_BF16(a2, b2, acc[2][2], 0, 0, 0);
    acc[2][3] = MFMA_BF16(a2, b3, acc[2][3], 0, 0, 0);
    acc[3][0] = MFMA_BF16(a3, b0, acc[3][0], 0, 0, 0);
    acc[3][1] = MFMA_BF16(a3, b1, acc[3][1], 0, 0, 0);
    acc[3][2] = MFMA_BF16(a3, b2, acc[3][2], 0, 0, 0);
    acc[3][3] = MFMA_BF16(a3, b3, acc[3][3], 0, 0, 0);
    __builtin_amdgcn_s_setprio(0);
    if (tt + 2 < niter) {
      asm volatile("s_waitcnt vmcnt(6)" ::: "memory");  // tile tt+1 landed; tt+2 in flight
    } else if (tt + 1 < niter) {
      asm volatile("s_waitcnt vmcnt(0)" ::: "memory");  // tail drain
    }
    if (tt + 1 < niter) {
      __builtin_amdgcn_s_barrier();
      __builtin_amdgcn_sched_barrier(0);
    }
    cur = (cur == 2) ? 0 : cur + 1;
  }
  // epilogue: C/D layout col=lane&15, row=quad*4+reg
  float bcol[4];
  #pragma unroll
  for (int j = 0; j < 4; j++) bcol[j] = bias[n0 + wn + j * 16 + l16];
  #pragma unroll
  for (int i = 0; i < 4; i++) {
    #pragma unroll
    for (int r = 0; r < 4; r++) {
      int row = m0 + wm + i * 16 + quad * 4 + r;
      #pragma unroll
      for (int j = 0; j < 4; j++) {
        int col = n0 + wn + j * 16 + l16;
        float v = acc[i][j][r] + bcol[j];
        if (ACT == 1) {
          // tanh-approx GELU via exp2 (|err| ~1e-3 << threshold slack)
          float e = v * (2.3022082f + 0.1029431f * v * v);
          float tt2 = exp2f(fminf(e, 80.0f));
          v = v * tt2 / (tt2 + 1.0f);
        }
        if (RESID == 1) v += b2f(((const u16*)resid)[(size_t)row * N + col]);
        if (RESID == 2) v += ((const float*)resid)[(size_t)row * N + col];
        if (OUTF32) ((float*)Cv)[(size_t)row * ldc + col] = v;
        else        ((u16*)Cv)[(size_t)row * ldc + col] = f2b(v);
      }
    }
  }
}

// ---------------- Flash attention: grid (B*H, S/64); qkv strided (ld=3072) ----------------
// LDS-staged K/VT tiles (global_load_lds, double-buffered, 1 barrier/iter).
// No-max softmax: scores hard-bounded (|s| <= |q||k|/8 ~ 18 by Cauchy-Schwarz on
// LN'd activations) so exp2 never overflows fp32; l reduced once at the end.
__global__ __launch_bounds__(256) void attn_k(const u16* __restrict__ QKV, const u16* __restrict__ VT,
                                              u16* __restrict__ ctx) {
  int bh = blockIdx.x;
  int b = bh >> 4;
  int q0 = blockIdx.y * 64;
  int t = threadIdx.x, wave = t >> 6, lane = t & 63, quad = lane >> 4, l16 = lane & 15;
  __shared__ u16 Ks[2][64 * 64];    // [key][d], XOR-swizzled chunks
  __shared__ u16 Vs[2][64 * 64];    // [d][key-of-tile], XOR-swizzled
  __shared__ u16 Plds[4][16][72];   // per-wave P strip (wave-private)
  const size_t base = ((size_t)b * 1024) * 3072 + (size_t)(bh & 15) * 64;
  const u16* Kbase = QKV + base + 1024;
  const u16* vtb = VT + (size_t)bh * 64 * 1024;
  int lrow = lane >> 3;                  // 0..7
  int lchunk = (lane & 7) ^ (lrow & 7);  // source-permute => phys chunk = logical ^ (row&7)
  int srow = wave * 16;                  // this wave's 16-row slab of the 64-row tile
  short8 qa[2];  // Q A-frags: A[m=l16][k=quad*8+j], k-halves 0/32
  #pragma unroll
  for (int kh = 0; kh < 2; kh++)
    qa[kh] = *(const short8*)(QKV + base + (size_t)(q0 + wave * 16 + l16) * 3072 + kh * 32 + quad * 8);
  #pragma unroll
  for (int half = 0; half < 2; half++) {
    int r8 = srow + half * 8;
    gload_lds16(Kbase + (size_t)(r8 + lrow) * 3072 + lchunk * 8, &Ks[0][r8 * 64]);
    gload_lds16(vtb + (size_t)(r8 + lrow) * 1024 + lchunk * 8, &Vs[0][r8 * 64]);
  }
  f32x4 o[4] = {};
  float l_acc[4] = {0.f, 0.f, 0.f, 0.f};
  for (int c = 0; c < 16; c++) {
    int buf = c & 1;
    __syncthreads();  // drains tile-c DMA; fences buf^1 readers from iter c-1
    if (c < 15) {
      #pragma unroll
      for (int half = 0; half < 2; half++) {
        int r8 = srow + half * 8;
        gload_lds16(Kbase + (size_t)((c + 1) * 64 + r8 + lrow) * 3072 + lchunk * 8, &Ks[buf ^ 1][r8 * 64]);
        gload_lds16(vtb + (size_t)(r8 + lrow) * 1024 + (c + 1) * 64 + lchunk * 8, &Vs[buf ^ 1][r8 * 64]);
      }
    }
    f32x4 s[4] = {};
    #pragma unroll
    for (int kh = 0; kh < 2; kh++)
      #pragma unroll
      for (int j = 0; j < 4; j++) {
        int row = j * 16 + l16;
        int pc = (kh * 4 + quad) ^ (row & 7);
        short8 kb = *(const short8*)(&Ks[buf][row * 64 + pc * 8]);
        s[j] = __builtin_amdgcn_mfma_f32_16x16x32_bf16(qa[kh], kb, s[j], 0, 0, 0);
      }
    #pragma unroll
    for (int j = 0; j < 4; j++)
      #pragma unroll
      for (int r = 0; r < 4; r++) {
        float p = exp2f(s[j][r] * 0.18033688011112042f);  // 2^(s*log2e/8)
        l_acc[r] += p;
        Plds[wave][quad * 4 + r][j * 16 + l16] = f2b(p);
      }
    #pragma unroll
    for (int kh = 0; kh < 2; kh++) {
      short8 pa = *(const short8*)(&Plds[wave][l16][kh * 32 + quad * 8]);
      #pragma unroll
      for (int d4 = 0; d4 < 4; d4++) {
        int row = d4 * 16 + l16;
        int pc = (kh * 4 + quad) ^ (row & 7);
        short8 vb = *(const short8*)(&Vs[buf][row * 64 + pc * 8]);
        o[d4] = __builtin_amdgcn_mfma_f32_16x16x32_bf16(pa, vb, o[d4], 0, 0, 0);
      }
    }
  }
  #pragma unroll
  for (int off = 1; off < 16; off <<= 1)
    #pragma unroll
    for (int r = 0; r < 4; r++) l_acc[r] += __shfl_xor(l_acc[r], off);
  #pragma unroll
  for (int r = 0; r < 4; r++) {
    float inv = 1.0f / l_acc[r];
    size_t row = (size_t)b * 1024 + q0 + wave * 16 + quad * 4 + r;
    #pragma unroll
    for (int d4 = 0; d4 < 4; d4++) {
      int col = (bh & 15) * 64 + d4 * 16 + l16;
      ctx[row * 1024 + col] = f2b(o[d4][r] * inv);
    }
  }
}

// ---------------- launch ----------------
// Inputs FP32, output FP32. Internal bf16. ws plan (<=144 MB, proven available):
//  [0,16)   h1 -> vt
//  [16,64)  qkv (ld 3072); after attn: x1@[16,32), h2@[32,48), W2T@[48,56)
//  [64,70)  WqkvT   [70,72) WoT   [72,80) W1T
//  [80,144) h3f (bqkv fp32 12KB parked at 80MB until FFN1 overwrites it - qkv gemm done by then)
// d_out: ctx bf16 [0,16M) -> final fp32 out (ctx dead after O-proj).
extern "C" void kernel_launch(void* const* d_in, const int* in_sizes, int n_in,
                              void* d_out, int out_size, void* d_ws, size_t ws_size,
                              hipStream_t stream) {
  const float* x   = (const float*)d_in[0];
  const float* Wq  = (const float*)d_in[1];  const float* bq  = (const float*)d_in[2];
  const float* Wk  = (const float*)d_in[3];  const float* bk  = (const float*)d_in[4];
  const float* Wv  = (const float*)d_in[5];  const float* bv  = (const float*)d_in[6];
  const float* Wo  = (const float*)d_in[7];  const float* bo  = (const float*)d_in[8];
  const float* W1  = (const float*)d_in[9];  const float* b1  = (const float*)d_in[10];
  const float* W2  = (const float*)d_in[11]; const float* b2  = (const float*)d_in[12];
  const float* g1  = (const float*)d_in[13]; const float* be1 = (const float*)d_in[14];
  const float* g2  = (const float*)d_in[15]; const float* be2 = (const float*)d_in[16];

  char* ws = (char*)d_ws;
  const size_t MB = 1024 * 1024;
  u16* h1    = (u16*)(ws + 0 * MB);
  u16* qkv   = (u16*)(ws + 16 * MB);
  u16* x1    = (u16*)(ws + 16 * MB);
  u16* h2    = (u16*)(ws + 32 * MB);
  u16* W2T   = (u16*)(ws + 48 * MB);
  u16* WqkvT = (u16*)(ws + 64 * MB);
  u16* WoT   = (u16*)(ws + 70 * MB);
  u16* W1T   = (u16*)(ws + 72 * MB);
  float* bqkv = (float*)(ws + 80 * MB);
  u16* h3f   = (u16*)(ws + 80 * MB);
  u16* vt    = h1;
  u16* ctx   = (u16*)d_out;
  float* out = (float*)d_out;

  transpose_k<<<dim3(32, 32), 256, 0, stream>>>(Wq, WqkvT, 1024, 1024);
  transpose_k<<<dim3(32, 32), 256, 0, stream>>>(Wk, WqkvT + (size_t)1024 * 1024, 1024, 1024);
  transpose_k<<<dim3(32, 32), 256, 0, stream>>>(Wv, WqkvT + (size_t)2048 * 1024, 1024, 1024);
  transpose_k<<<dim3(32, 32), 256, 0, stream>>>(Wo, WoT, 1024, 1024);
  transpose_k<<<dim3(128, 32), 256, 0, stream>>>(W1, W1T, 1024, 4096);
  cat3_k<<<12, 256, 0, stream>>>(bq, bk, bv, bqkv);

  ln_k<1><<<8192, 256, 0, stream>>>(x, g1, be1, h1);

  gemm_k<0, 0, 0><<<dim3(64, 12), 512, 0, stream>>>(h1, WqkvT, bqkv, nullptr, qkv,
                                                    8192, 3072, 1024, 3072);       // fused QKV

  vtrans_k<<<dim3(64, 128), 256, 0, stream>>>(qkv, vt);                            // vt = h1 (dead)

  attn_k<<<dim3(128, 16), 256, 0, stream>>>(qkv, vt, ctx);                         // ctx = d_out[0,16M)

  gemm_k<0, 2, 0><<<dim3(64, 4), 512, 0, stream>>>(ctx, WoT, bo, x, x1,
                                                   8192, 1024, 1024, 1024);        // x1 (+fp32 x)

  transpose_k<<<dim3(32, 128), 256, 0, stream>>>(W2, W2T, 4096, 1024);             // into dead v region

  ln_k<0><<<8192, 256, 0, stream>>>(x1, g2, be2, h2);

  gemm_k<1, 0, 0><<<dim3(64, 16), 512, 0, stream>>>(h2, W1T, b1, nullptr, h3f,
                                                    8192, 4096, 1024, 4096);       // FFN1 + GELU
  gemm_k<0, 1, 1><<<dim3(64, 4), 512, 0, stream>>>(h3f, W2T, b2, x1, out,
                                                   8192, 1024, 4096, 1024);        // FFN2 + resid

  (void)in_sizes; (void)n_in; (void)out_size; (void)ws_size;
}

// Round 4
// 546.649 us; speedup vs baseline: 1.0384x; 1.0384x over previous
//
#include <hip/hip_runtime.h>
#include <hip/hip_bf16.h>
#include <math.h>
#include <stdint.h>

typedef unsigned short u16;
typedef unsigned int u32;
typedef __attribute__((ext_vector_type(8))) short short8;   // 8 bf16 = 4 VGPRs (MFMA A/B frag)
typedef __attribute__((ext_vector_type(4))) float f32x4;    // MFMA C/D frag

__device__ __forceinline__ float b2f(u16 u) {
  union { u32 i; float f; } v; v.i = ((u32)u) << 16; return v.f;
}
__device__ __forceinline__ u16 f2b(float f) {
  union { float f; u32 i; } v; v.f = f;
  return (u16)((v.i + 0x7FFFu + ((v.i >> 16) & 1u)) >> 16);  // RNE
}

// async global->LDS DMA, 16B per lane; LDS dest = wave-uniform base + lane*16B
__device__ __forceinline__ void gload_lds16(const u16* g, u16* l) {
  __builtin_amdgcn_global_load_lds((const __attribute__((address_space(1))) void*)g,
                                   (__attribute__((address_space(3))) void*)l, 16, 0, 0);
}

#define LD8(p) (*(const short8*)(p))
#define MFMA_BF16 __builtin_amdgcn_mfma_f32_16x16x32_bf16

// ---------------- fused transpose+convert: fp32 (K x N) -> bf16 (N x K) ----------------
__global__ __launch_bounds__(256) void transpose_k(const float* __restrict__ in,
                                                   u16* __restrict__ out, int K, int N) {
  __shared__ u16 tile[32][33];
  int n0 = blockIdx.x * 32, k0 = blockIdx.y * 32;
  int tx = threadIdx.x & 31, ty = threadIdx.x >> 5;
  #pragma unroll
  for (int i = ty; i < 32; i += 8)
    tile[i][tx] = f2b(in[(size_t)(k0 + i) * N + n0 + tx]);
  __syncthreads();
  #pragma unroll
  for (int i = ty; i < 32; i += 8)
    out[(size_t)(n0 + i) * K + k0 + tx] = tile[tx][i];
}

// ---------------- concat 3 x 1024 fp32 biases ----------------
__global__ __launch_bounds__(256) void cat3_k(const float* __restrict__ a, const float* __restrict__ b,
                                              const float* __restrict__ c, float* __restrict__ o) {
  int i = blockIdx.x * 256 + threadIdx.x;
  o[i] = i < 1024 ? a[i] : (i < 2048 ? b[i - 1024] : c[i - 2048]);
}

// ---------------- per-head V transpose from strided qkv: v[s][2048+h*64+d] -> vt[(bh*64+d)][s] ----------------
__global__ __launch_bounds__(256) void vtrans_k(const u16* __restrict__ qkv, u16* __restrict__ vt) {
  __shared__ u16 tile[32][33];
  int bh = blockIdx.y, b = bh >> 4, h = bh & 15;
  int s0 = (blockIdx.x & 31) * 32, d0 = (blockIdx.x >> 5) * 32;
  int tx = threadIdx.x & 31, ty = threadIdx.x >> 5;
  #pragma unroll
  for (int i = ty; i < 32; i += 8)
    tile[i][tx] = qkv[(size_t)(b * 1024 + s0 + i) * 3072 + 2048 + h * 64 + d0 + tx];
  __syncthreads();
  #pragma unroll
  for (int i = ty; i < 32; i += 8)
    vt[(size_t)(bh * 64 + d0 + i) * 1024 + s0 + tx] = tile[tx][i];
}

// ---------------- LayerNorm over D=1024, one block per row; FP32IN: x fp32 vs bf16 ----------------
template<int FP32IN>
__global__ __launch_bounds__(256) void ln_k(const void* __restrict__ xv, const float* __restrict__ g,
                                            const float* __restrict__ be, u16* __restrict__ out) {
  int row = blockIdx.x, t = threadIdx.x;
  float f0, f1, f2, f3;
  if (FP32IN) {
    const float* xr = (const float*)xv + (size_t)row * 1024;
    float4 x4 = *(const float4*)(xr + t * 4);
    f0 = x4.x; f1 = x4.y; f2 = x4.z; f3 = x4.w;
  } else {
    const u16* xr = (const u16*)xv + (size_t)row * 1024;
    ushort4 x4 = *(const ushort4*)(xr + t * 4);
    f0 = b2f(x4.x); f1 = b2f(x4.y); f2 = b2f(x4.z); f3 = b2f(x4.w);
  }
  float s = f0 + f1 + f2 + f3;
  float ss = f0 * f0 + f1 * f1 + f2 * f2 + f3 * f3;
  #pragma unroll
  for (int off = 32; off > 0; off >>= 1) { s += __shfl_down(s, off); ss += __shfl_down(ss, off); }
  __shared__ float sb[4], ssb[4];
  if ((t & 63) == 0) { sb[t >> 6] = s; ssb[t >> 6] = ss; }
  __syncthreads();
  s = sb[0] + sb[1] + sb[2] + sb[3];
  ss = ssb[0] + ssb[1] + ssb[2] + ssb[3];
  float mu = s * (1.0f / 1024.0f);
  float var = ss * (1.0f / 1024.0f) - mu * mu;
  float rstd = rsqrtf(var + 1e-5f);
  float4 gv = *(const float4*)(g + t * 4);
  float4 bv = *(const float4*)(be + t * 4);
  ushort4 o;
  o.x = f2b((f0 - mu) * rstd * gv.x + bv.x);
  o.y = f2b((f1 - mu) * rstd * gv.y + bv.y);
  o.z = f2b((f2 - mu) * rstd * gv.z + bv.z);
  o.w = f2b((f3 - mu) * rstd * gv.w + bv.w);
  *(ushort4*)(out + (size_t)row * 1024 + t * 4) = o;
}

// ======================= gemm128: proven round-1 structure + conflict-fix swizzle ==============
// C[M,N] = act(A[M,K] @ Bt[N,K]^T + bias) (+resid). 128x128 tile, BK=32, 4 waves, dbuf DMA,
// __syncthreads drain per K-step. Swizzle fix: at 64B row pitch, rows 4 apart alias mod 128B,
// so chunk XOR must use (row>>2)&3 (not row&3): residue = (row&1)*4 + (chunk^((row>>2)&3))
// covers all 8 granule slots 2x -> conflict-free (was 4-way, 8.4M conflicts measured r1).
template<int ACT, int RESID, int OUTF32>
__global__ __launch_bounds__(256) void gemm_k(const u16* __restrict__ A, const u16* __restrict__ Bt,
                                              const float* __restrict__ bias, const void* __restrict__ resid,
                                              void* __restrict__ Cv, int M, int N, int K, int ldc) {
  __shared__ u16 As[2][128 * 32];
  __shared__ u16 Bs[2][128 * 32];
  int Ny = N >> 7;
  int lin = blockIdx.y * 64 + blockIdx.x;
  int c8 = lin & 7, sblk = lin >> 3;
  int mq = sblk / Ny;
  int m0 = ((mq << 3) | c8) << 7;
  int n0 = (sblk - mq * Ny) << 7;
  int t = threadIdx.x;
  int wave = t >> 6, lane = t & 63, quad = lane >> 4, l16 = lane & 15;
  int wm = (wave >> 1) * 64, wn = (wave & 1) * 64;
  f32x4 acc[4][4] = {};
  int lr = lane >> 2;                          // 0..15: row within 16-row slab
  int lc = (lane & 3) ^ ((lane >> 4) & 3);     // source chunk = logical ^ ((row>>2)&3)
  const u16* Ab = A + (size_t)(m0 + wave * 16 + lr) * K + lc * 8;
  const u16* Bb = Bt + (size_t)(n0 + wave * 16 + lr) * K + lc * 8;
  const int lb = wave * 16 * 32;               // wave-uniform LDS slab base (elements)
  const int rdoff = (quad ^ ((l16 >> 2) & 3)) * 8;
  #pragma unroll
  for (int i = 0; i < 2; i++) {
    gload_lds16(Ab + (size_t)i * 64 * K, &As[0][lb + i * 64 * 32]);
    gload_lds16(Bb + (size_t)i * 64 * K, &Bs[0][lb + i * 64 * 32]);
  }
  const int niter = K >> 5;
  for (int c = 0; c < niter; c++) {
    int buf = c & 1;
    __syncthreads();                      // drains DMA(c); fences buf^1 readers of iter c-1
    if (c + 1 < niter) {
      int k1 = (c + 1) << 5;
      #pragma unroll
      for (int i = 0; i < 2; i++) {
        gload_lds16(Ab + k1 + (size_t)i * 64 * K, &As[buf ^ 1][lb + i * 64 * 32]);
        gload_lds16(Bb + k1 + (size_t)i * 64 * K, &Bs[buf ^ 1][lb + i * 64 * 32]);
      }
    }
    short8 a[4], b[4];
    #pragma unroll
    for (int i = 0; i < 4; i++)
      a[i] = LD8(&As[buf][(wm + i * 16 + l16) * 32 + rdoff]);
    #pragma unroll
    for (int j = 0; j < 4; j++)
      b[j] = LD8(&Bs[buf][(wn + j * 16 + l16) * 32 + rdoff]);
    #pragma unroll
    for (int i = 0; i < 4; i++)
      #pragma unroll
      for (int j = 0; j < 4; j++)
        acc[i][j] = MFMA_BF16(a[i], b[j], acc[i][j], 0, 0, 0);
  }
  float bcol[4];
  #pragma unroll
  for (int j = 0; j < 4; j++) bcol[j] = bias[n0 + wn + j * 16 + l16];
  #pragma unroll
  for (int i = 0; i < 4; i++) {
    #pragma unroll
    for (int r = 0; r < 4; r++) {
      int row = m0 + wm + i * 16 + quad * 4 + r;
      #pragma unroll
      for (int j = 0; j < 4; j++) {
        int col = n0 + wn + j * 16 + l16;
        float v = acc[i][j][r] + bcol[j];
        if (ACT == 1) {
          float e = v * (2.3022082f + 0.1029431f * v * v);
          float tt = exp2f(fminf(e, 80.0f));
          v = v * tt / (tt + 1.0f);
        }
        if (RESID == 1) v += b2f(((const u16*)resid)[(size_t)row * N + col]);
        if (RESID == 2) v += ((const float*)resid)[(size_t)row * N + col];
        if (OUTF32) ((float*)Cv)[(size_t)row * ldc + col] = v;
        else        ((u16*)Cv)[(size_t)row * ldc + col] = f2b(v);
      }
    }
  }
}

// ======================= gemm256: faithful m201 geometry (T2+T3+T4+T5) =========================
// BM=BN=256, BK=32, 8 waves (512 thr) as 2M x 4N, per-wave 128x64 out (acc[8][4]), 16-MFMA
// clusters. LDS: 4 buffers x (A 16KB + B 16KB) = 128KB, 1 block/CU. Prefetch depth 3 K-tiles
// (12 loads/wave in flight); vmcnt(8) once per K-tile -> tile t+1 landed, t+2/t+3 in flight;
// loads issued ~3 tiles (~1500cy) before use, covering HBM latency. Never drains to 0 until tail.
// Buffer written at tile t ((t+3)&3) was read at t-1, retired before t's first barrier (WAR-safe);
// every wave does its own vmcnt BEFORE the shared barrier (cross-wave landing).
// 2 phases/tile, each: {8|4 ds_read_b128 || 2 gloads -> s_barrier -> lgkmcnt(0) -> sched_barrier
// -> setprio(1) -> 16 MFMA -> setprio(0) -> s_barrier}. Conflict-free chunk XOR ((row>>2)&3).
// Grid dim3(32, N/256), nwg % 8 == 0 -> bijective XCD remap.
template<int ACT, int RESID, int OUTF32>
__global__ __launch_bounds__(512, 2) void gemm256_k(const u16* __restrict__ A, const u16* __restrict__ Bt,
                                                    const float* __restrict__ bias, const void* __restrict__ resid,
                                                    void* __restrict__ Cv, int M, int N, int K, int ldc) {
  __shared__ u16 As[4][256 * 32];   // 4 x 16KB
  __shared__ u16 Bs[4][256 * 32];   // 4 x 16KB
  int Ny = N >> 8;
  int lin = blockIdx.y * 32 + blockIdx.x;
  int c8 = lin & 7, sblk = lin >> 3;
  int mq = sblk / Ny;
  int m0 = ((mq << 3) | c8) << 8;
  int n0 = (sblk - mq * Ny) << 8;
  int t = threadIdx.x;
  int wave = t >> 6, lane = t & 63, quad = lane >> 4, l16 = lane & 15;
  int wm = (wave >> 2) << 7;            // 0 | 128
  int wn = (wave & 3) << 6;             // 0 | 64 | 128 | 192
  f32x4 acc[8][4] = {};
  int lr = lane >> 2;                          // 0..15
  int lc = (lane & 3) ^ ((lane >> 4) & 3);     // src chunk = logical ^ ((row>>2)&3)
  const u16* Ab = A + (size_t)(m0 + wave * 16 + lr) * K + lc * 8;
  const u16* Bb = Bt + (size_t)(n0 + wave * 16 + lr) * K + lc * 8;
  const int lbA = wave * 16 * 32;              // wave slab base; instr g adds g*128 rows
  const int cswz = (quad ^ ((l16 >> 2) & 3)) * 8;
  const int rdA = (wm + l16) * 32 + cswz;      // + i*512
  const int rdB = (wn + l16) * 32 + cswz;      // + j*512
  const int niter = K >> 5;
  // ---- prologue: stage tiles 0,1,2 (12 gloads/wave) ----
  #pragma unroll
  for (int p = 0; p < 3; p++) {
    #pragma unroll
    for (int g = 0; g < 2; g++) {
      gload_lds16(Ab + (p << 5) + (size_t)g * 128 * K, &As[p][lbA + g * 128 * 32]);
      gload_lds16(Bb + (p << 5) + (size_t)g * 128 * K, &Bs[p][lbA + g * 128 * 32]);
    }
  }
  asm volatile("s_waitcnt vmcnt(8)" ::: "memory");   // tile0 landed; 1,2 in flight
  __builtin_amdgcn_s_barrier();
  __builtin_amdgcn_sched_barrier(0);
  for (int tt = 0; tt < niter; tt++) {
    int buf = tt & 3, wb = (tt + 3) & 3;
    const bool pf = (tt + 3 < niter);
    const int kpf = (tt + 3) << 5;
    const u16* Ac = &As[buf][0];
    const u16* Bc = &Bs[buf][0];
    short8 a[8], b[4];
    // ---------- phase 1: rows 0-3, all b ; stage A of tile tt+3 ----------
    a[0] = LD8(Ac + rdA);
    a[1] = LD8(Ac + rdA + 512);
    a[2] = LD8(Ac + rdA + 1024);
    a[3] = LD8(Ac + rdA + 1536);
    b[0] = LD8(Bc + rdB);
    b[1] = LD8(Bc + rdB + 512);
    b[2] = LD8(Bc + rdB + 1024);
    b[3] = LD8(Bc + rdB + 1536);
    if (pf) {
      gload_lds16(Ab + kpf, &As[wb][lbA]);
      gload_lds16(Ab + kpf + (size_t)128 * K, &As[wb][lbA + 128 * 32]);
    }
    __builtin_amdgcn_s_barrier();
    asm volatile("s_waitcnt lgkmcnt(0)" ::: "memory");
    __builtin_amdgcn_sched_barrier(0);
    __builtin_amdgcn_s_setprio(1);
    #pragma unroll
    for (int i = 0; i < 4; i++)
      #pragma unroll
      for (int j = 0; j < 4; j++)
        acc[i][j] = MFMA_BF16(a[i], b[j], acc[i][j], 0, 0, 0);
    __builtin_amdgcn_s_setprio(0);
    __builtin_amdgcn_s_barrier();
    __builtin_amdgcn_sched_barrier(0);
    // ---------- phase 2: rows 4-7 ; stage B of tile tt+3 ----------
    a[4] = LD8(Ac + rdA + 2048);
    a[5] = LD8(Ac + rdA + 2560);
    a[6] = LD8(Ac + rdA + 3072);
    a[7] = LD8(Ac + rdA + 3584);
    if (pf) {
      gload_lds16(Bb + kpf, &Bs[wb][lbA]);
      gload_lds16(Bb + kpf + (size_t)128 * K, &Bs[wb][lbA + 128 * 32]);
    }
    __builtin_amdgcn_s_barrier();
    asm volatile("s_waitcnt lgkmcnt(0)" ::: "memory");
    __builtin_amdgcn_sched_barrier(0);
    __builtin_amdgcn_s_setprio(1);
    #pragma unroll
    for (int i = 4; i < 8; i++)
      #pragma unroll
      for (int j = 0; j < 4; j++)
        acc[i][j] = MFMA_BF16(a[i], b[j], acc[i][j], 0, 0, 0);
    __builtin_amdgcn_s_setprio(0);
    if (tt + 3 < niter) {
      asm volatile("s_waitcnt vmcnt(8)" ::: "memory");   // tile tt+1 landed
    } else if (tt + 2 < niter) {
      asm volatile("s_waitcnt vmcnt(4)" ::: "memory");
    } else if (tt + 1 < niter) {
      asm volatile("s_waitcnt vmcnt(0)" ::: "memory");
    }
    if (tt + 1 < niter) {
      __builtin_amdgcn_s_barrier();
      __builtin_amdgcn_sched_barrier(0);
    }
  }
  // epilogue: C/D layout col=lane&15, row=quad*4+reg
  float bcol[4];
  #pragma unroll
  for (int j = 0; j < 4; j++) bcol[j] = bias[n0 + wn + j * 16 + l16];
  #pragma unroll
  for (int i = 0; i < 8; i++) {
    #pragma unroll
    for (int r = 0; r < 4; r++) {
      int row = m0 + wm + i * 16 + quad * 4 + r;
      #pragma unroll
      for (int j = 0; j < 4; j++) {
        int col = n0 + wn + j * 16 + l16;
        float v = acc[i][j][r] + bcol[j];
        if (ACT == 1) {
          float e = v * (2.3022082f + 0.1029431f * v * v);
          float tt2 = exp2f(fminf(e, 80.0f));
          v = v * tt2 / (tt2 + 1.0f);
        }
        if (RESID == 1) v += b2f(((const u16*)resid)[(size_t)row * N + col]);
        if (RESID == 2) v += ((const float*)resid)[(size_t)row * N + col];
        if (OUTF32) ((float*)Cv)[(size_t)row * ldc + col] = v;
        else        ((u16*)Cv)[(size_t)row * ldc + col] = f2b(v);
      }
    }
  }
}

// ---------------- Flash attention: grid (B*H, S/64); qkv strided (ld=3072) ----------------
__global__ __launch_bounds__(256) void attn_k(const u16* __restrict__ QKV, const u16* __restrict__ VT,
                                              u16* __restrict__ ctx) {
  int bh = blockIdx.x;
  int b = bh >> 4;
  int q0 = blockIdx.y * 64;
  int t = threadIdx.x, wave = t >> 6, lane = t & 63, quad = lane >> 4, l16 = lane & 15;
  __shared__ u16 Ks[2][64 * 64];    // [key][d], XOR-swizzled chunks
  __shared__ u16 Vs[2][64 * 64];    // [d][key-of-tile], XOR-swizzled
  __shared__ u16 Plds[4][16][72];   // per-wave P strip (wave-private)
  const size_t base = ((size_t)b * 1024) * 3072 + (size_t)(bh & 15) * 64;
  const u16* Kbase = QKV + base + 1024;
  const u16* vtb = VT + (size_t)bh * 64 * 1024;
  int lrow = lane >> 3;                  // 0..7
  int lchunk = (lane & 7) ^ (lrow & 7);  // source-permute => phys chunk = logical ^ (row&7)
  int srow = wave * 16;                  // this wave's 16-row slab of the 64-row tile
  short8 qa[2];  // Q A-frags
  #pragma unroll
  for (int kh = 0; kh < 2; kh++)
    qa[kh] = *(const short8*)(QKV + base + (size_t)(q0 + wave * 16 + l16) * 3072 + kh * 32 + quad * 8);
  #pragma unroll
  for (int half = 0; half < 2; half++) {
    int r8 = srow + half * 8;
    gload_lds16(Kbase + (size_t)(r8 + lrow) * 3072 + lchunk * 8, &Ks[0][r8 * 64]);
    gload_lds16(vtb + (size_t)(r8 + lrow) * 1024 + lchunk * 8, &Vs[0][r8 * 64]);
  }
  f32x4 o[4] = {};
  float l_acc[4] = {0.f, 0.f, 0.f, 0.f};
  for (int c = 0; c < 16; c++) {
    int buf = c & 1;
    __syncthreads();  // drains tile-c DMA; fences buf^1 readers from iter c-1
    if (c < 15) {
      #pragma unroll
      for (int half = 0; half < 2; half++) {
        int r8 = srow + half * 8;
        gload_lds16(Kbase + (size_t)((c + 1) * 64 + r8 + lrow) * 3072 + lchunk * 8, &Ks[buf ^ 1][r8 * 64]);
        gload_lds16(vtb + (size_t)(r8 + lrow) * 1024 + (c + 1) * 64 + lchunk * 8, &Vs[buf ^ 1][r8 * 64]);
      }
    }
    f32x4 s[4] = {};
    #pragma unroll
    for (int kh = 0; kh < 2; kh++)
      #pragma unroll
      for (int j = 0; j < 4; j++) {
        int row = j * 16 + l16;
        int pc = (kh * 4 + quad) ^ (row & 7);
        short8 kb = *(const short8*)(&Ks[buf][row * 64 + pc * 8]);
        s[j] = MFMA_BF16(qa[kh], kb, s[j], 0, 0, 0);
      }
    #pragma unroll
    for (int j = 0; j < 4; j++)
      #pragma unroll
      for (int r = 0; r < 4; r++) {
        float p = exp2f(s[j][r] * 0.18033688011112042f);  // 2^(s*log2e/8)
        l_acc[r] += p;
        Plds[wave][quad * 4 + r][j * 16 + l16] = f2b(p);
      }
    #pragma unroll
    for (int kh = 0; kh < 2; kh++) {
      short8 pa = *(const short8*)(&Plds[wave][l16][kh * 32 + quad * 8]);
      #pragma unroll
      for (int d4 = 0; d4 < 4; d4++) {
        int row = d4 * 16 + l16;
        int pc = (kh * 4 + quad) ^ (row & 7);
        short8 vb = *(const short8*)(&Vs[buf][row * 64 + pc * 8]);
        o[d4] = MFMA_BF16(pa, vb, o[d4], 0, 0, 0);
      }
    }
  }
  #pragma unroll
  for (int off = 1; off < 16; off <<= 1)
    #pragma unroll
    for (int r = 0; r < 4; r++) l_acc[r] += __shfl_xor(l_acc[r], off);
  #pragma unroll
  for (int r = 0; r < 4; r++) {
    float inv = 1.0f / l_acc[r];
    size_t row = (size_t)b * 1024 + q0 + wave * 16 + quad * 4 + r;
    #pragma unroll
    for (int d4 = 0; d4 < 4; d4++) {
      int col = (bh & 15) * 64 + d4 * 16 + l16;
      ctx[row * 1024 + col] = f2b(o[d4][r] * inv);
    }
  }
}

// ---------------- launch ----------------
extern "C" void kernel_launch(void* const* d_in, const int* in_sizes, int n_in,
                              void* d_out, int out_size, void* d_ws, size_t ws_size,
                              hipStream_t stream) {
  const float* x   = (const float*)d_in[0];
  const float* Wq  = (const float*)d_in[1];  const float* bq  = (const float*)d_in[2];
  const float* Wk  = (const float*)d_in[3];  const float* bk  = (const float*)d_in[4];
  const float* Wv  = (const float*)d_in[5];  const float* bv  = (const float*)d_in[6];
  const float* Wo  = (const float*)d_in[7];  const float* bo  = (const float*)d_in[8];
  const float* W1  = (const float*)d_in[9];  const float* b1  = (const float*)d_in[10];
  const float* W2  = (const float*)d_in[11]; const float* b2  = (const float*)d_in[12];
  const float* g1  = (const float*)d_in[13]; const float* be1 = (const float*)d_in[14];
  const float* g2  = (const float*)d_in[15]; const float* be2 = (const float*)d_in[16];

  char* ws = (char*)d_ws;
  const size_t MB = 1024 * 1024;
  u16* h1    = (u16*)(ws + 0 * MB);
  u16* qkv   = (u16*)(ws + 16 * MB);
  u16* x1    = (u16*)(ws + 16 * MB);
  u16* h2    = (u16*)(ws + 32 * MB);
  u16* W2T   = (u16*)(ws + 48 * MB);
  u16* WqkvT = (u16*)(ws + 64 * MB);
  u16* WoT   = (u16*)(ws + 70 * MB);
  u16* W1T   = (u16*)(ws + 72 * MB);
  float* bqkv = (float*)(ws + 80 * MB);
  u16* h3f   = (u16*)(ws + 80 * MB);
  u16* vt    = h1;
  u16* ctx   = (u16*)d_out;
  float* out = (float*)d_out;

  transpose_k<<<dim3(32, 32), 256, 0, stream>>>(Wq, WqkvT, 1024, 1024);
  transpose_k<<<dim3(32, 32), 256, 0, stream>>>(Wk, WqkvT + (size_t)1024 * 1024, 1024, 1024);
  transpose_k<<<dim3(32, 32), 256, 0, stream>>>(Wv, WqkvT + (size_t)2048 * 1024, 1024, 1024);
  transpose_k<<<dim3(32, 32), 256, 0, stream>>>(Wo, WoT, 1024, 1024);
  transpose_k<<<dim3(128, 32), 256, 0, stream>>>(W1, W1T, 1024, 4096);
  cat3_k<<<12, 256, 0, stream>>>(bq, bk, bv, bqkv);

  ln_k<1><<<8192, 256, 0, stream>>>(x, g1, be1, h1);

  gemm256_k<0, 0, 0><<<dim3(32, 12), 512, 0, stream>>>(h1, WqkvT, bqkv, nullptr, qkv,
                                                       8192, 3072, 1024, 3072);    // fused QKV

  vtrans_k<<<dim3(64, 128), 256, 0, stream>>>(qkv, vt);                            // vt = h1 (dead)

  attn_k<<<dim3(128, 16), 256, 0, stream>>>(qkv, vt, ctx);                         // ctx = d_out[0,16M)

  gemm_k<0, 2, 0><<<dim3(64, 8), 256, 0, stream>>>(ctx, WoT, bo, x, x1,
                                                   8192, 1024, 1024, 1024);        // x1 (+fp32 x)

  transpose_k<<<dim3(32, 128), 256, 0, stream>>>(W2, W2T, 4096, 1024);             // into dead v region

  ln_k<0><<<8192, 256, 0, stream>>>(x1, g2, be2, h2);

  gemm256_k<1, 0, 0><<<dim3(32, 16), 512, 0, stream>>>(h2, W1T, b1, nullptr, h3f,
                                                       8192, 4096, 1024, 4096);    // FFN1 + GELU
  gemm_k<0, 1, 1><<<dim3(64, 8), 256, 0, stream>>>(h3f, W2T, b2, x1, out,
                                                   8192, 1024, 4096, 1024);        // FFN2 + resid

  (void)in_sizes; (void)n_in; (void)out_size; (void)ws_size;
}

// Round 5
// 545.777 us; speedup vs baseline: 1.0400x; 1.0016x over previous
//
#include <hip/hip_runtime.h>
#include <hip/hip_bf16.h>
#include <math.h>
#include <stdint.h>

typedef unsigned short u16;
typedef unsigned int u32;
typedef __attribute__((ext_vector_type(8))) short short8;   // 8 bf16 = 4 VGPRs (MFMA A/B frag)
typedef __attribute__((ext_vector_type(4))) float f32x4;    // MFMA C/D frag

__device__ __forceinline__ float b2f(u16 u) {
  union { u32 i; float f; } v; v.i = ((u32)u) << 16; return v.f;
}
__device__ __forceinline__ u16 f2b(float f) {
  union { float f; u32 i; } v; v.f = f;
  return (u16)((v.i + 0x7FFFu + ((v.i >> 16) & 1u)) >> 16);  // RNE
}

// async global->LDS DMA, 16B per lane; LDS dest = wave-uniform base + lane*16B
__device__ __forceinline__ void gload_lds16(const u16* g, u16* l) {
  __builtin_amdgcn_global_load_lds((const __attribute__((address_space(1))) void*)g,
                                   (__attribute__((address_space(3))) void*)l, 16, 0, 0);
}

#define LD8(p) (*(const short8*)(p))
#define MFMA_BF16 __builtin_amdgcn_mfma_f32_16x16x32_bf16

// ---------------- fused transpose+convert: fp32 (K x N) -> bf16 (N x K) ----------------
__global__ __launch_bounds__(256) void transpose_k(const float* __restrict__ in,
                                                   u16* __restrict__ out, int K, int N) {
  __shared__ u16 tile[32][33];
  int n0 = blockIdx.x * 32, k0 = blockIdx.y * 32;
  int tx = threadIdx.x & 31, ty = threadIdx.x >> 5;
  #pragma unroll
  for (int i = ty; i < 32; i += 8)
    tile[i][tx] = f2b(in[(size_t)(k0 + i) * N + n0 + tx]);
  __syncthreads();
  #pragma unroll
  for (int i = ty; i < 32; i += 8)
    out[(size_t)(n0 + i) * K + k0 + tx] = tile[tx][i];
}

// ---------------- concat 3 x 1024 fp32 biases ----------------
__global__ __launch_bounds__(256) void cat3_k(const float* __restrict__ a, const float* __restrict__ b,
                                              const float* __restrict__ c, float* __restrict__ o) {
  int i = blockIdx.x * 256 + threadIdx.x;
  o[i] = i < 1024 ? a[i] : (i < 2048 ? b[i - 1024] : c[i - 2048]);
}

// ---------------- per-head V transpose from strided qkv: v[s][2048+h*64+d] -> vt[(bh*64+d)][s] ----------------
__global__ __launch_bounds__(256) void vtrans_k(const u16* __restrict__ qkv, u16* __restrict__ vt) {
  __shared__ u16 tile[32][33];
  int bh = blockIdx.y, b = bh >> 4, h = bh & 15;
  int s0 = (blockIdx.x & 31) * 32, d0 = (blockIdx.x >> 5) * 32;
  int tx = threadIdx.x & 31, ty = threadIdx.x >> 5;
  #pragma unroll
  for (int i = ty; i < 32; i += 8)
    tile[i][tx] = qkv[(size_t)(b * 1024 + s0 + i) * 3072 + 2048 + h * 64 + d0 + tx];
  __syncthreads();
  #pragma unroll
  for (int i = ty; i < 32; i += 8)
    vt[(size_t)(bh * 64 + d0 + i) * 1024 + s0 + tx] = tile[tx][i];
}

// ---------------- LayerNorm over D=1024, one block per row; FP32IN: x fp32 vs bf16 ----------------
template<int FP32IN>
__global__ __launch_bounds__(256) void ln_k(const void* __restrict__ xv, const float* __restrict__ g,
                                            const float* __restrict__ be, u16* __restrict__ out) {
  int row = blockIdx.x, t = threadIdx.x;
  float f0, f1, f2, f3;
  if (FP32IN) {
    const float* xr = (const float*)xv + (size_t)row * 1024;
    float4 x4 = *(const float4*)(xr + t * 4);
    f0 = x4.x; f1 = x4.y; f2 = x4.z; f3 = x4.w;
  } else {
    const u16* xr = (const u16*)xv + (size_t)row * 1024;
    ushort4 x4 = *(const ushort4*)(xr + t * 4);
    f0 = b2f(x4.x); f1 = b2f(x4.y); f2 = b2f(x4.z); f3 = b2f(x4.w);
  }
  float s = f0 + f1 + f2 + f3;
  float ss = f0 * f0 + f1 * f1 + f2 * f2 + f3 * f3;
  #pragma unroll
  for (int off = 32; off > 0; off >>= 1) { s += __shfl_down(s, off); ss += __shfl_down(ss, off); }
  __shared__ float sb[4], ssb[4];
  if ((t & 63) == 0) { sb[t >> 6] = s; ssb[t >> 6] = ss; }
  __syncthreads();
  s = sb[0] + sb[1] + sb[2] + sb[3];
  ss = ssb[0] + ssb[1] + ssb[2] + ssb[3];
  float mu = s * (1.0f / 1024.0f);
  float var = ss * (1.0f / 1024.0f) - mu * mu;
  float rstd = rsqrtf(var + 1e-5f);
  float4 gv = *(const float4*)(g + t * 4);
  float4 bv = *(const float4*)(be + t * 4);
  ushort4 o;
  o.x = f2b((f0 - mu) * rstd * gv.x + bv.x);
  o.y = f2b((f1 - mu) * rstd * gv.y + bv.y);
  o.z = f2b((f2 - mu) * rstd * gv.z + bv.z);
  o.w = f2b((f3 - mu) * rstd * gv.w + bv.w);
  *(ushort4*)(out + (size_t)row * 1024 + t * 4) = o;
}

// ======================= gemm128: round-1 structure + CORRECT conflict-free swizzle ============
// BK=32 -> LDS row pitch 64B, bank window 128B spans TWO rows: slot = (row&1)*4 + phys_chunk.
// b128 serviced 8 lanes/cycle => need 8 consecutive lanes (8 consecutive rows, fixed quad) on
// 8 distinct slots => chunk XOR must be ((row>>1)&3) (rows 0,2,4,6 -> 0,1,2,3). The old
// ((row>>2)&3) was constant across row pairs -> uniform 2-way conflict (8.4M/6.3M measured).
// row = wm + i*16 + l16: wm,i*16 contribute 0 to (row>>1)&3 => per-lane constant is valid.
template<int ACT, int RESID, int OUTF32>
__global__ __launch_bounds__(256) void gemm_k(const u16* __restrict__ A, const u16* __restrict__ Bt,
                                              const float* __restrict__ bias, const void* __restrict__ resid,
                                              void* __restrict__ Cv, int M, int N, int K, int ldc) {
  __shared__ u16 As[2][128 * 32];
  __shared__ u16 Bs[2][128 * 32];
  int Ny = N >> 7;
  int lin = blockIdx.y * 64 + blockIdx.x;
  int c8 = lin & 7, sblk = lin >> 3;
  int mq = sblk / Ny;
  int m0 = ((mq << 3) | c8) << 7;
  int n0 = (sblk - mq * Ny) << 7;
  int t = threadIdx.x;
  int wave = t >> 6, lane = t & 63, quad = lane >> 4, l16 = lane & 15;
  int wm = (wave >> 1) * 64, wn = (wave & 1) * 64;
  f32x4 acc[4][4] = {};
  int lr = lane >> 2;                          // 0..15: row within 16-row slab
  int lc = (lane & 3) ^ ((lane >> 3) & 3);     // source chunk = logical ^ ((row>>1)&3)
  const u16* Ab = A + (size_t)(m0 + wave * 16 + lr) * K + lc * 8;
  const u16* Bb = Bt + (size_t)(n0 + wave * 16 + lr) * K + lc * 8;
  const int lb = wave * 16 * 32;               // wave-uniform LDS slab base (elements)
  const int rdoff = (quad ^ ((l16 >> 1) & 3)) * 8;
  #pragma unroll
  for (int i = 0; i < 2; i++) {
    gload_lds16(Ab + (size_t)i * 64 * K, &As[0][lb + i * 64 * 32]);
    gload_lds16(Bb + (size_t)i * 64 * K, &Bs[0][lb + i * 64 * 32]);
  }
  const int niter = K >> 5;
  for (int c = 0; c < niter; c++) {
    int buf = c & 1;
    __syncthreads();                      // drains DMA(c); fences buf^1 readers of iter c-1
    if (c + 1 < niter) {
      int k1 = (c + 1) << 5;
      #pragma unroll
      for (int i = 0; i < 2; i++) {
        gload_lds16(Ab + k1 + (size_t)i * 64 * K, &As[buf ^ 1][lb + i * 64 * 32]);
        gload_lds16(Bb + k1 + (size_t)i * 64 * K, &Bs[buf ^ 1][lb + i * 64 * 32]);
      }
    }
    short8 a[4], b[4];
    #pragma unroll
    for (int i = 0; i < 4; i++)
      a[i] = LD8(&As[buf][(wm + i * 16 + l16) * 32 + rdoff]);
    #pragma unroll
    for (int j = 0; j < 4; j++)
      b[j] = LD8(&Bs[buf][(wn + j * 16 + l16) * 32 + rdoff]);
    #pragma unroll
    for (int i = 0; i < 4; i++)
      #pragma unroll
      for (int j = 0; j < 4; j++)
        acc[i][j] = MFMA_BF16(a[i], b[j], acc[i][j], 0, 0, 0);
  }
  float bcol[4];
  #pragma unroll
  for (int j = 0; j < 4; j++) bcol[j] = bias[n0 + wn + j * 16 + l16];
  #pragma unroll
  for (int i = 0; i < 4; i++) {
    #pragma unroll
    for (int r = 0; r < 4; r++) {
      int row = m0 + wm + i * 16 + quad * 4 + r;
      #pragma unroll
      for (int j = 0; j < 4; j++) {
        int col = n0 + wn + j * 16 + l16;
        float v = acc[i][j][r] + bcol[j];
        if (ACT == 1) {
          float e = v * (2.3022082f + 0.1029431f * v * v);
          float tt = exp2f(fminf(e, 80.0f));
          v = v * tt / (tt + 1.0f);
        }
        if (RESID == 1) v += b2f(((const u16*)resid)[(size_t)row * N + col]);
        if (RESID == 2) v += ((const float*)resid)[(size_t)row * N + col];
        if (OUTF32) ((float*)Cv)[(size_t)row * ldc + col] = v;
        else        ((u16*)Cv)[(size_t)row * ldc + col] = f2b(v);
      }
    }
  }
}

// ======================= gemm256: m201 geometry + CORRECT conflict-free swizzle ================
// BM=BN=256, BK=32, 8 waves as 2M x 4N, per-wave 128x64 (acc[8][4]), 16-MFMA clusters.
// 4 LDS buffers (128KB), prefetch depth 3, vmcnt(8) once per K-tile (never 0 until tail).
// Swizzle: chunk XOR ((row>>1)&3) -- see gemm128 comment; slot=(row&1)*4+physchunk bijective
// over every 8 consecutive rows. WAR-safe: buf (tt+3)&3 was read at tt-1, retired before tt's
// first barrier; per-wave vmcnt BEFORE shared barrier covers cross-wave landing.
template<int ACT, int RESID, int OUTF32>
__global__ __launch_bounds__(512, 2) void gemm256_k(const u16* __restrict__ A, const u16* __restrict__ Bt,
                                                    const float* __restrict__ bias, const void* __restrict__ resid,
                                                    void* __restrict__ Cv, int M, int N, int K, int ldc) {
  __shared__ u16 As[4][256 * 32];   // 4 x 16KB
  __shared__ u16 Bs[4][256 * 32];   // 4 x 16KB
  int Ny = N >> 8;
  int lin = blockIdx.y * 32 + blockIdx.x;
  int c8 = lin & 7, sblk = lin >> 3;
  int mq = sblk / Ny;
  int m0 = ((mq << 3) | c8) << 8;
  int n0 = (sblk - mq * Ny) << 8;
  int t = threadIdx.x;
  int wave = t >> 6, lane = t & 63, quad = lane >> 4, l16 = lane & 15;
  int wm = (wave >> 2) << 7;            // 0 | 128
  int wn = (wave & 3) << 6;             // 0 | 64 | 128 | 192
  f32x4 acc[8][4] = {};
  int lr = lane >> 2;                          // 0..15
  int lc = (lane & 3) ^ ((lane >> 3) & 3);     // src chunk = logical ^ ((row>>1)&3)
  const u16* Ab = A + (size_t)(m0 + wave * 16 + lr) * K + lc * 8;
  const u16* Bb = Bt + (size_t)(n0 + wave * 16 + lr) * K + lc * 8;
  const int lbA = wave * 16 * 32;              // wave slab base; instr g adds g*128 rows
  const int cswz = (quad ^ ((l16 >> 1) & 3)) * 8;
  const int rdA = (wm + l16) * 32 + cswz;      // + i*512
  const int rdB = (wn + l16) * 32 + cswz;      // + j*512
  const int niter = K >> 5;
  // ---- prologue: stage tiles 0,1,2 (12 gloads/wave) ----
  #pragma unroll
  for (int p = 0; p < 3; p++) {
    #pragma unroll
    for (int g = 0; g < 2; g++) {
      gload_lds16(Ab + (p << 5) + (size_t)g * 128 * K, &As[p][lbA + g * 128 * 32]);
      gload_lds16(Bb + (p << 5) + (size_t)g * 128 * K, &Bs[p][lbA + g * 128 * 32]);
    }
  }
  asm volatile("s_waitcnt vmcnt(8)" ::: "memory");   // tile0 landed; 1,2 in flight
  __builtin_amdgcn_s_barrier();
  __builtin_amdgcn_sched_barrier(0);
  for (int tt = 0; tt < niter; tt++) {
    int buf = tt & 3, wb = (tt + 3) & 3;
    const bool pf = (tt + 3 < niter);
    const int kpf = (tt + 3) << 5;
    const u16* Ac = &As[buf][0];
    const u16* Bc = &Bs[buf][0];
    short8 a[8], b[4];
    // ---------- phase 1: rows 0-3, all b ; stage A of tile tt+3 ----------
    a[0] = LD8(Ac + rdA);
    a[1] = LD8(Ac + rdA + 512);
    a[2] = LD8(Ac + rdA + 1024);
    a[3] = LD8(Ac + rdA + 1536);
    b[0] = LD8(Bc + rdB);
    b[1] = LD8(Bc + rdB + 512);
    b[2] = LD8(Bc + rdB + 1024);
    b[3] = LD8(Bc + rdB + 1536);
    if (pf) {
      gload_lds16(Ab + kpf, &As[wb][lbA]);
      gload_lds16(Ab + kpf + (size_t)128 * K, &As[wb][lbA + 128 * 32]);
    }
    __builtin_amdgcn_s_barrier();
    asm volatile("s_waitcnt lgkmcnt(0)" ::: "memory");
    __builtin_amdgcn_sched_barrier(0);
    __builtin_amdgcn_s_setprio(1);
    #pragma unroll
    for (int i = 0; i < 4; i++)
      #pragma unroll
      for (int j = 0; j < 4; j++)
        acc[i][j] = MFMA_BF16(a[i], b[j], acc[i][j], 0, 0, 0);
    __builtin_amdgcn_s_setprio(0);
    __builtin_amdgcn_s_barrier();
    __builtin_amdgcn_sched_barrier(0);
    // ---------- phase 2: rows 4-7 ; stage B of tile tt+3 ----------
    a[4] = LD8(Ac + rdA + 2048);
    a[5] = LD8(Ac + rdA + 2560);
    a[6] = LD8(Ac + rdA + 3072);
    a[7] = LD8(Ac + rdA + 3584);
    if (pf) {
      gload_lds16(Bb + kpf, &Bs[wb][lbA]);
      gload_lds16(Bb + kpf + (size_t)128 * K, &Bs[wb][lbA + 128 * 32]);
    }
    __builtin_amdgcn_s_barrier();
    asm volatile("s_waitcnt lgkmcnt(0)" ::: "memory");
    __builtin_amdgcn_sched_barrier(0);
    __builtin_amdgcn_s_setprio(1);
    #pragma unroll
    for (int i = 4; i < 8; i++)
      #pragma unroll
      for (int j = 0; j < 4; j++)
        acc[i][j] = MFMA_BF16(a[i], b[j], acc[i][j], 0, 0, 0);
    __builtin_amdgcn_s_setprio(0);
    if (tt + 3 < niter) {
      asm volatile("s_waitcnt vmcnt(8)" ::: "memory");   // tile tt+1 landed
    } else if (tt + 2 < niter) {
      asm volatile("s_waitcnt vmcnt(4)" ::: "memory");
    } else if (tt + 1 < niter) {
      asm volatile("s_waitcnt vmcnt(0)" ::: "memory");
    }
    if (tt + 1 < niter) {
      __builtin_amdgcn_s_barrier();
      __builtin_amdgcn_sched_barrier(0);
    }
  }
  // epilogue: C/D layout col=lane&15, row=quad*4+reg
  float bcol[4];
  #pragma unroll
  for (int j = 0; j < 4; j++) bcol[j] = bias[n0 + wn + j * 16 + l16];
  #pragma unroll
  for (int i = 0; i < 8; i++) {
    #pragma unroll
    for (int r = 0; r < 4; r++) {
      int row = m0 + wm + i * 16 + quad * 4 + r;
      #pragma unroll
      for (int j = 0; j < 4; j++) {
        int col = n0 + wn + j * 16 + l16;
        float v = acc[i][j][r] + bcol[j];
        if (ACT == 1) {
          float e = v * (2.3022082f + 0.1029431f * v * v);
          float tt2 = exp2f(fminf(e, 80.0f));
          v = v * tt2 / (tt2 + 1.0f);
        }
        if (RESID == 1) v += b2f(((const u16*)resid)[(size_t)row * N + col]);
        if (RESID == 2) v += ((const float*)resid)[(size_t)row * N + col];
        if (OUTF32) ((float*)Cv)[(size_t)row * ldc + col] = v;
        else        ((u16*)Cv)[(size_t)row * ldc + col] = f2b(v);
      }
    }
  }
}

// ---------------- Flash attention: grid (B*H, S/64); qkv strided (ld=3072) ----------------
__global__ __launch_bounds__(256) void attn_k(const u16* __restrict__ QKV, const u16* __restrict__ VT,
                                              u16* __restrict__ ctx) {
  int bh = blockIdx.x;
  int b = bh >> 4;
  int q0 = blockIdx.y * 64;
  int t = threadIdx.x, wave = t >> 6, lane = t & 63, quad = lane >> 4, l16 = lane & 15;
  __shared__ u16 Ks[2][64 * 64];    // [key][d], XOR-swizzled chunks
  __shared__ u16 Vs[2][64 * 64];    // [d][key-of-tile], XOR-swizzled
  __shared__ u16 Plds[4][16][72];   // per-wave P strip (wave-private)
  const size_t base = ((size_t)b * 1024) * 3072 + (size_t)(bh & 15) * 64;
  const u16* Kbase = QKV + base + 1024;
  const u16* vtb = VT + (size_t)bh * 64 * 1024;
  int lrow = lane >> 3;                  // 0..7
  int lchunk = (lane & 7) ^ (lrow & 7);  // source-permute => phys chunk = logical ^ (row&7)
  int srow = wave * 16;                  // this wave's 16-row slab of the 64-row tile
  short8 qa[2];  // Q A-frags
  #pragma unroll
  for (int kh = 0; kh < 2; kh++)
    qa[kh] = *(const short8*)(QKV + base + (size_t)(q0 + wave * 16 + l16) * 3072 + kh * 32 + quad * 8);
  #pragma unroll
  for (int half = 0; half < 2; half++) {
    int r8 = srow + half * 8;
    gload_lds16(Kbase + (size_t)(r8 + lrow) * 3072 + lchunk * 8, &Ks[0][r8 * 64]);
    gload_lds16(vtb + (size_t)(r8 + lrow) * 1024 + lchunk * 8, &Vs[0][r8 * 64]);
  }
  f32x4 o[4] = {};
  float l_acc[4] = {0.f, 0.f, 0.f, 0.f};
  for (int c = 0; c < 16; c++) {
    int buf = c & 1;
    __syncthreads();  // drains tile-c DMA; fences buf^1 readers from iter c-1
    if (c < 15) {
      #pragma unroll
      for (int half = 0; half < 2; half++) {
        int r8 = srow + half * 8;
        gload_lds16(Kbase + (size_t)((c + 1) * 64 + r8 + lrow) * 3072 + lchunk * 8, &Ks[buf ^ 1][r8 * 64]);
        gload_lds16(vtb + (size_t)(r8 + lrow) * 1024 + (c + 1) * 64 + lchunk * 8, &Vs[buf ^ 1][r8 * 64]);
      }
    }
    f32x4 s[4] = {};
    #pragma unroll
    for (int kh = 0; kh < 2; kh++)
      #pragma unroll
      for (int j = 0; j < 4; j++) {
        int row = j * 16 + l16;
        int pc = (kh * 4 + quad) ^ (row & 7);
        short8 kb = *(const short8*)(&Ks[buf][row * 64 + pc * 8]);
        s[j] = MFMA_BF16(qa[kh], kb, s[j], 0, 0, 0);
      }
    #pragma unroll
    for (int j = 0; j < 4; j++)
      #pragma unroll
      for (int r = 0; r < 4; r++) {
        float p = exp2f(s[j][r] * 0.18033688011112042f);  // 2^(s*log2e/8)
        l_acc[r] += p;
        Plds[wave][quad * 4 + r][j * 16 + l16] = f2b(p);
      }
    #pragma unroll
    for (int kh = 0; kh < 2; kh++) {
      short8 pa = *(const short8*)(&Plds[wave][l16][kh * 32 + quad * 8]);
      #pragma unroll
      for (int d4 = 0; d4 < 4; d4++) {
        int row = d4 * 16 + l16;
        int pc = (kh * 4 + quad) ^ (row & 7);
        short8 vb = *(const short8*)(&Vs[buf][row * 64 + pc * 8]);
        o[d4] = MFMA_BF16(pa, vb, o[d4], 0, 0, 0);
      }
    }
  }
  #pragma unroll
  for (int off = 1; off < 16; off <<= 1)
    #pragma unroll
    for (int r = 0; r < 4; r++) l_acc[r] += __shfl_xor(l_acc[r], off);
  #pragma unroll
  for (int r = 0; r < 4; r++) {
    float inv = 1.0f / l_acc[r];
    size_t row = (size_t)b * 1024 + q0 + wave * 16 + quad * 4 + r;
    #pragma unroll
    for (int d4 = 0; d4 < 4; d4++) {
      int col = (bh & 15) * 64 + d4 * 16 + l16;
      ctx[row * 1024 + col] = f2b(o[d4][r] * inv);
    }
  }
}

// ---------------- launch ----------------
extern "C" void kernel_launch(void* const* d_in, const int* in_sizes, int n_in,
                              void* d_out, int out_size, void* d_ws, size_t ws_size,
                              hipStream_t stream) {
  const float* x   = (const float*)d_in[0];
  const float* Wq  = (const float*)d_in[1];  const float* bq  = (const float*)d_in[2];
  const float* Wk  = (const float*)d_in[3];  const float* bk  = (const float*)d_in[4];
  const float* Wv  = (const float*)d_in[5];  const float* bv  = (const float*)d_in[6];
  const float* Wo  = (const float*)d_in[7];  const float* bo  = (const float*)d_in[8];
  const float* W1  = (const float*)d_in[9];  const float* b1  = (const float*)d_in[10];
  const float* W2  = (const float*)d_in[11]; const float* b2  = (const float*)d_in[12];
  const float* g1  = (const float*)d_in[13]; const float* be1 = (const float*)d_in[14];
  const float* g2  = (const float*)d_in[15]; const float* be2 = (const float*)d_in[16];

  char* ws = (char*)d_ws;
  const size_t MB = 1024 * 1024;
  u16* h1    = (u16*)(ws + 0 * MB);
  u16* qkv   = (u16*)(ws + 16 * MB);
  u16* x1    = (u16*)(ws + 16 * MB);
  u16* h2    = (u16*)(ws + 32 * MB);
  u16* W2T   = (u16*)(ws + 48 * MB);
  u16* WqkvT = (u16*)(ws + 64 * MB);
  u16* WoT   = (u16*)(ws + 70 * MB);
  u16* W1T   = (u16*)(ws + 72 * MB);
  float* bqkv = (float*)(ws + 80 * MB);
  u16* h3f   = (u16*)(ws + 80 * MB);
  u16* vt    = h1;
  u16* ctx   = (u16*)d_out;
  float* out = (float*)d_out;

  transpose_k<<<dim3(32, 32), 256, 0, stream>>>(Wq, WqkvT, 1024, 1024);
  transpose_k<<<dim3(32, 32), 256, 0, stream>>>(Wk, WqkvT + (size_t)1024 * 1024, 1024, 1024);
  transpose_k<<<dim3(32, 32), 256, 0, stream>>>(Wv, WqkvT + (size_t)2048 * 1024, 1024, 1024);
  transpose_k<<<dim3(32, 32), 256, 0, stream>>>(Wo, WoT, 1024, 1024);
  transpose_k<<<dim3(128, 32), 256, 0, stream>>>(W1, W1T, 1024, 4096);
  cat3_k<<<12, 256, 0, stream>>>(bq, bk, bv, bqkv);

  ln_k<1><<<8192, 256, 0, stream>>>(x, g1, be1, h1);

  gemm256_k<0, 0, 0><<<dim3(32, 12), 512, 0, stream>>>(h1, WqkvT, bqkv, nullptr, qkv,
                                                       8192, 3072, 1024, 3072);    // fused QKV

  vtrans_k<<<dim3(64, 128), 256, 0, stream>>>(qkv, vt);                            // vt = h1 (dead)

  attn_k<<<dim3(128, 16), 256, 0, stream>>>(qkv, vt, ctx);                         // ctx = d_out[0,16M)

  gemm_k<0, 2, 0><<<dim3(64, 8), 256, 0, stream>>>(ctx, WoT, bo, x, x1,
                                                   8192, 1024, 1024, 1024);        // x1 (+fp32 x)

  transpose_k<<<dim3(32, 128), 256, 0, stream>>>(W2, W2T, 4096, 1024);             // into dead v region

  ln_k<0><<<8192, 256, 0, stream>>>(x1, g2, be2, h2);

  gemm256_k<1, 0, 0><<<dim3(32, 16), 512, 0, stream>>>(h2, W1T, b1, nullptr, h3f,
                                                       8192, 4096, 1024, 4096);    // FFN1 + GELU
  gemm_k<0, 1, 1><<<dim3(64, 8), 256, 0, stream>>>(h3f, W2T, b2, x1, out,
                                                   8192, 1024, 4096, 1024);        // FFN2 + resid

  (void)in_sizes; (void)n_in; (void)out_size; (void)ws_size;
}

// Round 6
// 536.999 us; speedup vs baseline: 1.0570x; 1.0163x over previous
//
#include <hip/hip_runtime.h>
#include <hip/hip_bf16.h>
#include <math.h>
#include <stdint.h>

typedef unsigned short u16;
typedef unsigned int u32;
typedef __attribute__((ext_vector_type(8))) short short8;   // 8 bf16 = 4 VGPRs (MFMA A/B frag)
typedef __attribute__((ext_vector_type(4))) float f32x4;    // MFMA C/D frag

__device__ __forceinline__ float b2f(u16 u) {
  union { u32 i; float f; } v; v.i = ((u32)u) << 16; return v.f;
}
__device__ __forceinline__ u16 f2b(float f) {
  union { float f; u32 i; } v; v.f = f;
  return (u16)((v.i + 0x7FFFu + ((v.i >> 16) & 1u)) >> 16);  // RNE
}

// async global->LDS DMA, 16B per lane; LDS dest = wave-uniform base + lane*16B
__device__ __forceinline__ void gload_lds16(const u16* g, u16* l) {
  __builtin_amdgcn_global_load_lds((const __attribute__((address_space(1))) void*)g,
                                   (__attribute__((address_space(3))) void*)l, 16, 0, 0);
}

#define LD8(p) (*(const short8*)(p))
#define MFMA_BF16 __builtin_amdgcn_mfma_f32_16x16x32_bf16

// ---------------- fused transpose+convert: fp32 (K x N) -> bf16 (N x K) ----------------
__global__ __launch_bounds__(256) void transpose_k(const float* __restrict__ in,
                                                   u16* __restrict__ out, int K, int N) {
  __shared__ u16 tile[32][33];
  int n0 = blockIdx.x * 32, k0 = blockIdx.y * 32;
  int tx = threadIdx.x & 31, ty = threadIdx.x >> 5;
  #pragma unroll
  for (int i = ty; i < 32; i += 8)
    tile[i][tx] = f2b(in[(size_t)(k0 + i) * N + n0 + tx]);
  __syncthreads();
  #pragma unroll
  for (int i = ty; i < 32; i += 8)
    out[(size_t)(n0 + i) * K + k0 + tx] = tile[tx][i];
}

// ---------------- concat 3 x 1024 fp32 biases ----------------
__global__ __launch_bounds__(256) void cat3_k(const float* __restrict__ a, const float* __restrict__ b,
                                              const float* __restrict__ c, float* __restrict__ o) {
  int i = blockIdx.x * 256 + threadIdx.x;
  o[i] = i < 1024 ? a[i] : (i < 2048 ? b[i - 1024] : c[i - 2048]);
}

// ---------------- per-head V transpose from strided qkv: v[s][2048+h*64+d] -> vt[(bh*64+d)][s] ----------------
__global__ __launch_bounds__(256) void vtrans_k(const u16* __restrict__ qkv, u16* __restrict__ vt) {
  __shared__ u16 tile[32][33];
  int bh = blockIdx.y, b = bh >> 4, h = bh & 15;
  int s0 = (blockIdx.x & 31) * 32, d0 = (blockIdx.x >> 5) * 32;
  int tx = threadIdx.x & 31, ty = threadIdx.x >> 5;
  #pragma unroll
  for (int i = ty; i < 32; i += 8)
    tile[i][tx] = qkv[(size_t)(b * 1024 + s0 + i) * 3072 + 2048 + h * 64 + d0 + tx];
  __syncthreads();
  #pragma unroll
  for (int i = ty; i < 32; i += 8)
    vt[(size_t)(bh * 64 + d0 + i) * 1024 + s0 + tx] = tile[tx][i];
}

// ---------------- LayerNorm over D=1024, one block per row; FP32IN: x fp32 vs bf16 ----------------
template<int FP32IN>
__global__ __launch_bounds__(256) void ln_k(const void* __restrict__ xv, const float* __restrict__ g,
                                            const float* __restrict__ be, u16* __restrict__ out) {
  int row = blockIdx.x, t = threadIdx.x;
  float f0, f1, f2, f3;
  if (FP32IN) {
    const float* xr = (const float*)xv + (size_t)row * 1024;
    float4 x4 = *(const float4*)(xr + t * 4);
    f0 = x4.x; f1 = x4.y; f2 = x4.z; f3 = x4.w;
  } else {
    const u16* xr = (const u16*)xv + (size_t)row * 1024;
    ushort4 x4 = *(const ushort4*)(xr + t * 4);
    f0 = b2f(x4.x); f1 = b2f(x4.y); f2 = b2f(x4.z); f3 = b2f(x4.w);
  }
  float s = f0 + f1 + f2 + f3;
  float ss = f0 * f0 + f1 * f1 + f2 * f2 + f3 * f3;
  #pragma unroll
  for (int off = 32; off > 0; off >>= 1) { s += __shfl_down(s, off); ss += __shfl_down(ss, off); }
  __shared__ float sb[4], ssb[4];
  if ((t & 63) == 0) { sb[t >> 6] = s; ssb[t >> 6] = ss; }
  __syncthreads();
  s = sb[0] + sb[1] + sb[2] + sb[3];
  ss = ssb[0] + ssb[1] + ssb[2] + ssb[3];
  float mu = s * (1.0f / 1024.0f);
  float var = ss * (1.0f / 1024.0f) - mu * mu;
  float rstd = rsqrtf(var + 1e-5f);
  float4 gv = *(const float4*)(g + t * 4);
  float4 bv = *(const float4*)(be + t * 4);
  ushort4 o;
  o.x = f2b((f0 - mu) * rstd * gv.x + bv.x);
  o.y = f2b((f1 - mu) * rstd * gv.y + bv.y);
  o.z = f2b((f2 - mu) * rstd * gv.z + bv.z);
  o.w = f2b((f3 - mu) * rstd * gv.w + bv.w);
  *(ushort4*)(out + (size_t)row * 1024 + t * 4) = o;
}

// ======================= gemm128: round-1 structure + conflict-free swizzle ====================
// (frozen; used for O-proj and FFN2)
template<int ACT, int RESID, int OUTF32>
__global__ __launch_bounds__(256) void gemm_k(const u16* __restrict__ A, const u16* __restrict__ Bt,
                                              const float* __restrict__ bias, const void* __restrict__ resid,
                                              void* __restrict__ Cv, int M, int N, int K, int ldc) {
  __shared__ u16 As[2][128 * 32];
  __shared__ u16 Bs[2][128 * 32];
  int Ny = N >> 7;
  int lin = blockIdx.y * 64 + blockIdx.x;
  int c8 = lin & 7, sblk = lin >> 3;
  int mq = sblk / Ny;
  int m0 = ((mq << 3) | c8) << 7;
  int n0 = (sblk - mq * Ny) << 7;
  int t = threadIdx.x;
  int wave = t >> 6, lane = t & 63, quad = lane >> 4, l16 = lane & 15;
  int wm = (wave >> 1) * 64, wn = (wave & 1) * 64;
  f32x4 acc[4][4] = {};
  int lr = lane >> 2;                          // 0..15: row within 16-row slab
  int lc = (lane & 3) ^ ((lane >> 3) & 3);     // source chunk = logical ^ ((row>>1)&3)
  const u16* Ab = A + (size_t)(m0 + wave * 16 + lr) * K + lc * 8;
  const u16* Bb = Bt + (size_t)(n0 + wave * 16 + lr) * K + lc * 8;
  const int lb = wave * 16 * 32;               // wave-uniform LDS slab base (elements)
  const int rdoff = (quad ^ ((l16 >> 1) & 3)) * 8;
  #pragma unroll
  for (int i = 0; i < 2; i++) {
    gload_lds16(Ab + (size_t)i * 64 * K, &As[0][lb + i * 64 * 32]);
    gload_lds16(Bb + (size_t)i * 64 * K, &Bs[0][lb + i * 64 * 32]);
  }
  const int niter = K >> 5;
  for (int c = 0; c < niter; c++) {
    int buf = c & 1;
    __syncthreads();                      // drains DMA(c); fences buf^1 readers of iter c-1
    if (c + 1 < niter) {
      int k1 = (c + 1) << 5;
      #pragma unroll
      for (int i = 0; i < 2; i++) {
        gload_lds16(Ab + k1 + (size_t)i * 64 * K, &As[buf ^ 1][lb + i * 64 * 32]);
        gload_lds16(Bb + k1 + (size_t)i * 64 * K, &Bs[buf ^ 1][lb + i * 64 * 32]);
      }
    }
    short8 a[4], b[4];
    #pragma unroll
    for (int i = 0; i < 4; i++)
      a[i] = LD8(&As[buf][(wm + i * 16 + l16) * 32 + rdoff]);
    #pragma unroll
    for (int j = 0; j < 4; j++)
      b[j] = LD8(&Bs[buf][(wn + j * 16 + l16) * 32 + rdoff]);
    #pragma unroll
    for (int i = 0; i < 4; i++)
      #pragma unroll
      for (int j = 0; j < 4; j++)
        acc[i][j] = MFMA_BF16(a[i], b[j], acc[i][j], 0, 0, 0);
  }
  float bcol[4];
  #pragma unroll
  for (int j = 0; j < 4; j++) bcol[j] = bias[n0 + wn + j * 16 + l16];
  #pragma unroll
  for (int i = 0; i < 4; i++) {
    #pragma unroll
    for (int r = 0; r < 4; r++) {
      int row = m0 + wm + i * 16 + quad * 4 + r;
      #pragma unroll
      for (int j = 0; j < 4; j++) {
        int col = n0 + wn + j * 16 + l16;
        float v = acc[i][j][r] + bcol[j];
        if (ACT == 1) {
          float e = v * (2.3022082f + 0.1029431f * v * v);
          float tt = exp2f(fminf(e, 80.0f));
          v = v * tt / (tt + 1.0f);
        }
        if (RESID == 1) v += b2f(((const u16*)resid)[(size_t)row * N + col]);
        if (RESID == 2) v += ((const float*)resid)[(size_t)row * N + col];
        if (OUTF32) ((float*)Cv)[(size_t)row * ldc + col] = v;
        else        ((u16*)Cv)[(size_t)row * ldc + col] = f2b(v);
      }
    }
  }
}

// ======================= gemm256_k8: faithful BK=64 4-phase schedule (m201/T3+T4+T5) ===========
// BM=BN=256, BK=64, 8 waves (2M x 4N), per-wave 128x64 (acc[8][4]). LDS: 2 buffers x
// (A 32KB + B 32KB) = 128KB, 1 block/CU. Per K-tile, 4 phases of 16 MFMA:
//   P0: ds_read a0-3/b0-3 @kk0 || stage next tile's A (4 gloads) -> bar -> lgkm0 -> MFMA
//   P1: ds_read a4-7 @kk0      || stage next tile's B (4 gloads) -> bar -> lgkm0 -> MFMA
//   P2: ds_read a0-3/b0-3 @kk1                                  -> bar -> lgkm0 -> MFMA
//   P3: ds_read a4-7 @kk1                                       -> bar -> lgkm0 -> MFMA
// Boundary: vmcnt(0)+barrier -- waited loads were issued in P0/P1, >=2 phases (~600+cy) of
// cover, so the drain is cheap (unlike r1's 80-cy-old loads). WAR-safe: buf^1 written at tile
// t was fully read at t-1 (reads retired by t-1's P3 lgkm0 + boundary barrier). Cross-wave:
// each wave's own vmcnt(0) precedes the shared barrier. Swizzle (128B row pitch): phys chunk =
// logical ^ (row&7) on both stage-source and ds_read -- measured 0 conflicts (r3/r5).
template<int ACT, int RESID, int OUTF32>
__global__ __launch_bounds__(512, 2) void gemm256_k(const u16* __restrict__ A, const u16* __restrict__ Bt,
                                                    const float* __restrict__ bias, const void* __restrict__ resid,
                                                    void* __restrict__ Cv, int M, int N, int K, int ldc) {
  __shared__ u16 As[2][256 * 64];   // 2 x 32KB
  __shared__ u16 Bs[2][256 * 64];   // 2 x 32KB
  int Ny = N >> 8;
  int lin = blockIdx.y * 32 + blockIdx.x;
  int c8 = lin & 7, sblk = lin >> 3;
  int mq = sblk / Ny;
  int m0 = ((mq << 3) | c8) << 8;
  int n0 = (sblk - mq * Ny) << 8;
  int t = threadIdx.x;
  int wave = t >> 6, lane = t & 63, quad = lane >> 4, l16 = lane & 15;
  int wm = (wave >> 2) << 7;            // 0 | 128
  int wn = (wave & 3) << 6;             // 0 | 64 | 128 | 192
  f32x4 acc[8][4] = {};
  int lrow = lane >> 3;                        // 0..7
  int lchunk = (lane & 7) ^ lrow;              // src chunk = logical ^ (row&7)
  const u16* Ab = A + (size_t)(m0 + wave * 32 + lrow) * K + lchunk * 8;
  const u16* Bb = Bt + (size_t)(n0 + wave * 32 + lrow) * K + lchunk * 8;
  const int sbase = wave * 32 * 64;            // wave's staging slab base (elements); +g*8*64
  const int x7 = l16 & 7;
  const int rdA = (wm + l16) * 64;             // + i*1024 + cswz
  const int rdB = (wn + l16) * 64;             // + j*1024 + cswz
  const int cz0 = (quad ^ x7) * 8;             // kk=0: logical chunk = quad
  const int cz1 = ((4 + quad) ^ x7) * 8;       // kk=1: logical chunk = 4+quad
  const int niter = K >> 6;
  // ---- prologue: stage tile 0 into buf0 (8 gloads/wave) ----
  #pragma unroll
  for (int g = 0; g < 4; g++) {
    gload_lds16(Ab + (size_t)g * 8 * K, &As[0][sbase + g * 8 * 64]);
    gload_lds16(Bb + (size_t)g * 8 * K, &Bs[0][sbase + g * 8 * 64]);
  }
  asm volatile("s_waitcnt vmcnt(0)" ::: "memory");
  __builtin_amdgcn_s_barrier();
  __builtin_amdgcn_sched_barrier(0);
  for (int tt = 0; tt < niter; tt++) {
    int buf = tt & 1;
    const bool pf = (tt + 1 < niter);
    const int kpf = (tt + 1) << 6;
    const u16* Ac = &As[buf][0];
    const u16* Bc = &Bs[buf][0];
    u16* Aw = &As[buf ^ 1][0];
    u16* Bw = &Bs[buf ^ 1][0];
    short8 a0, a1, a2, a3, a4, a5, a6, a7, b0, b1, b2, b3;
    // ---------- P0: kk=0 i0-3 + all b ; stage A(tile tt+1) ----------
    a0 = LD8(Ac + rdA + cz0);
    a1 = LD8(Ac + rdA + 1024 + cz0);
    a2 = LD8(Ac + rdA + 2048 + cz0);
    a3 = LD8(Ac + rdA + 3072 + cz0);
    b0 = LD8(Bc + rdB + cz0);
    b1 = LD8(Bc + rdB + 1024 + cz0);
    b2 = LD8(Bc + rdB + 2048 + cz0);
    b3 = LD8(Bc + rdB + 3072 + cz0);
    if (pf) {
      #pragma unroll
      for (int g = 0; g < 4; g++)
        gload_lds16(Ab + kpf + (size_t)g * 8 * K, Aw + sbase + g * 8 * 64);
    }
    __builtin_amdgcn_s_barrier();
    asm volatile("s_waitcnt lgkmcnt(0)" ::: "memory");
    __builtin_amdgcn_sched_barrier(0);
    __builtin_amdgcn_s_setprio(1);
    acc[0][0] = MFMA_BF16(a0, b0, acc[0][0], 0, 0, 0);
    acc[0][1] = MFMA_BF16(a0, b1, acc[0][1], 0, 0, 0);
    acc[0][2] = MFMA_BF16(a0, b2, acc[0][2], 0, 0, 0);
    acc[0][3] = MFMA_BF16(a0, b3, acc[0][3], 0, 0, 0);
    acc[1][0] = MFMA_BF16(a1, b0, acc[1][0], 0, 0, 0);
    acc[1][1] = MFMA_BF16(a1, b1, acc[1][1], 0, 0, 0);
    acc[1][2] = MFMA_BF16(a1, b2, acc[1][2], 0, 0, 0);
    acc[1][3] = MFMA_BF16(a1, b3, acc[1][3], 0, 0, 0);
    acc[2][0] = MFMA_BF16(a2, b0, acc[2][0], 0, 0, 0);
    acc[2][1] = MFMA_BF16(a2, b1, acc[2][1], 0, 0, 0);
    acc[2][2] = MFMA_BF16(a2, b2, acc[2][2], 0, 0, 0);
    acc[2][3] = MFMA_BF16(a2, b3, acc[2][3], 0, 0, 0);
    acc[3][0] = MFMA_BF16(a3, b0, acc[3][0], 0, 0, 0);
    acc[3][1] = MFMA_BF16(a3, b1, acc[3][1], 0, 0, 0);
    acc[3][2] = MFMA_BF16(a3, b2, acc[3][2], 0, 0, 0);
    acc[3][3] = MFMA_BF16(a3, b3, acc[3][3], 0, 0, 0);
    __builtin_amdgcn_s_setprio(0);
    __builtin_amdgcn_s_barrier();
    __builtin_amdgcn_sched_barrier(0);
    // ---------- P1: kk=0 i4-7 ; stage B(tile tt+1) ----------
    a4 = LD8(Ac + rdA + 4096 + cz0);
    a5 = LD8(Ac + rdA + 5120 + cz0);
    a6 = LD8(Ac + rdA + 6144 + cz0);
    a7 = LD8(Ac + rdA + 7168 + cz0);
    if (pf) {
      #pragma unroll
      for (int g = 0; g < 4; g++)
        gload_lds16(Bb + kpf + (size_t)g * 8 * K, Bw + sbase + g * 8 * 64);
    }
    __builtin_amdgcn_s_barrier();
    asm volatile("s_waitcnt lgkmcnt(0)" ::: "memory");
    __builtin_amdgcn_sched_barrier(0);
    __builtin_amdgcn_s_setprio(1);
    acc[4][0] = MFMA_BF16(a4, b0, acc[4][0], 0, 0, 0);
    acc[4][1] = MFMA_BF16(a4, b1, acc[4][1], 0, 0, 0);
    acc[4][2] = MFMA_BF16(a4, b2, acc[4][2], 0, 0, 0);
    acc[4][3] = MFMA_BF16(a4, b3, acc[4][3], 0, 0, 0);
    acc[5][0] = MFMA_BF16(a5, b0, acc[5][0], 0, 0, 0);
    acc[5][1] = MFMA_BF16(a5, b1, acc[5][1], 0, 0, 0);
    acc[5][2] = MFMA_BF16(a5, b2, acc[5][2], 0, 0, 0);
    acc[5][3] = MFMA_BF16(a5, b3, acc[5][3], 0, 0, 0);
    acc[6][0] = MFMA_BF16(a6, b0, acc[6][0], 0, 0, 0);
    acc[6][1] = MFMA_BF16(a6, b1, acc[6][1], 0, 0, 0);
    acc[6][2] = MFMA_BF16(a6, b2, acc[6][2], 0, 0, 0);
    acc[6][3] = MFMA_BF16(a6, b3, acc[6][3], 0, 0, 0);
    acc[7][0] = MFMA_BF16(a7, b0, acc[7][0], 0, 0, 0);
    acc[7][1] = MFMA_BF16(a7, b1, acc[7][1], 0, 0, 0);
    acc[7][2] = MFMA_BF16(a7, b2, acc[7][2], 0, 0, 0);
    acc[7][3] = MFMA_BF16(a7, b3, acc[7][3], 0, 0, 0);
    __builtin_amdgcn_s_setprio(0);
    __builtin_amdgcn_s_barrier();
    __builtin_amdgcn_sched_barrier(0);
    // ---------- P2: kk=1 i0-3 + all b ----------
    a0 = LD8(Ac + rdA + cz1);
    a1 = LD8(Ac + rdA + 1024 + cz1);
    a2 = LD8(Ac + rdA + 2048 + cz1);
    a3 = LD8(Ac + rdA + 3072 + cz1);
    b0 = LD8(Bc + rdB + cz1);
    b1 = LD8(Bc + rdB + 1024 + cz1);
    b2 = LD8(Bc + rdB + 2048 + cz1);
    b3 = LD8(Bc + rdB + 3072 + cz1);
    __builtin_amdgcn_s_barrier();
    asm volatile("s_waitcnt lgkmcnt(0)" ::: "memory");
    __builtin_amdgcn_sched_barrier(0);
    __builtin_amdgcn_s_setprio(1);
    acc[0][0] = MFMA_BF16(a0, b0, acc[0][0], 0, 0, 0);
    acc[0][1] = MFMA_BF16(a0, b1, acc[0][1], 0, 0, 0);
    acc[0][2] = MFMA_BF16(a0, b2, acc[0][2], 0, 0, 0);
    acc[0][3] = MFMA_BF16(a0, b3, acc[0][3], 0, 0, 0);
    acc[1][0] = MFMA_BF16(a1, b0, acc[1][0], 0, 0, 0);
    acc[1][1] = MFMA_BF16(a1, b1, acc[1][1], 0, 0, 0);
    acc[1][2] = MFMA_BF16(a1, b2, acc[1][2], 0, 0, 0);
    acc[1][3] = MFMA_BF16(a1, b3, acc[1][3], 0, 0, 0);
    acc[2][0] = MFMA_BF16(a2, b0, acc[2][0], 0, 0, 0);
    acc[2][1] = MFMA_BF16(a2, b1, acc[2][1], 0, 0, 0);
    acc[2][2] = MFMA_BF16(a2, b2, acc[2][2], 0, 0, 0);
    acc[2][3] = MFMA_BF16(a2, b3, acc[2][3], 0, 0, 0);
    acc[3][0] = MFMA_BF16(a3, b0, acc[3][0], 0, 0, 0);
    acc[3][1] = MFMA_BF16(a3, b1, acc[3][1], 0, 0, 0);
    acc[3][2] = MFMA_BF16(a3, b2, acc[3][2], 0, 0, 0);
    acc[3][3] = MFMA_BF16(a3, b3, acc[3][3], 0, 0, 0);
    __builtin_amdgcn_s_setprio(0);
    __builtin_amdgcn_s_barrier();
    __builtin_amdgcn_sched_barrier(0);
    // ---------- P3: kk=1 i4-7 ; K-tile boundary ----------
    a4 = LD8(Ac + rdA + 4096 + cz1);
    a5 = LD8(Ac + rdA + 5120 + cz1);
    a6 = LD8(Ac + rdA + 6144 + cz1);
    a7 = LD8(Ac + rdA + 7168 + cz1);
    __builtin_amdgcn_s_barrier();
    asm volatile("s_waitcnt lgkmcnt(0)" ::: "memory");
    __builtin_amdgcn_sched_barrier(0);
    __builtin_amdgcn_s_setprio(1);
    acc[4][0] = MFMA_BF16(a4, b0, acc[4][0], 0, 0, 0);
    acc[4][1] = MFMA_BF16(a4, b1, acc[4][1], 0, 0, 0);
    acc[4][2] = MFMA_BF16(a4, b2, acc[4][2], 0, 0, 0);
    acc[4][3] = MFMA_BF16(a4, b3, acc[4][3], 0, 0, 0);
    acc[5][0] = MFMA_BF16(a5, b0, acc[5][0], 0, 0, 0);
    acc[5][1] = MFMA_BF16(a5, b1, acc[5][1], 0, 0, 0);
    acc[5][2] = MFMA_BF16(a5, b2, acc[5][2], 0, 0, 0);
    acc[5][3] = MFMA_BF16(a5, b3, acc[5][3], 0, 0, 0);
    acc[6][0] = MFMA_BF16(a6, b0, acc[6][0], 0, 0, 0);
    acc[6][1] = MFMA_BF16(a6, b1, acc[6][1], 0, 0, 0);
    acc[6][2] = MFMA_BF16(a6, b2, acc[6][2], 0, 0, 0);
    acc[6][3] = MFMA_BF16(a6, b3, acc[6][3], 0, 0, 0);
    acc[7][0] = MFMA_BF16(a7, b0, acc[7][0], 0, 0, 0);
    acc[7][1] = MFMA_BF16(a7, b1, acc[7][1], 0, 0, 0);
    acc[7][2] = MFMA_BF16(a7, b2, acc[7][2], 0, 0, 0);
    acc[7][3] = MFMA_BF16(a7, b3, acc[7][3], 0, 0, 0);
    __builtin_amdgcn_s_setprio(0);
    if (pf) {
      asm volatile("s_waitcnt vmcnt(0)" ::: "memory");  // loads issued >=2 phases ago
      __builtin_amdgcn_s_barrier();
      __builtin_amdgcn_sched_barrier(0);
    }
  }
  // epilogue: C/D layout col=lane&15, row=quad*4+reg
  float bcol[4];
  #pragma unroll
  for (int j = 0; j < 4; j++) bcol[j] = bias[n0 + wn + j * 16 + l16];
  #pragma unroll
  for (int i = 0; i < 8; i++) {
    #pragma unroll
    for (int r = 0; r < 4; r++) {
      int row = m0 + wm + i * 16 + quad * 4 + r;
      #pragma unroll
      for (int j = 0; j < 4; j++) {
        int col = n0 + wn + j * 16 + l16;
        float v = acc[i][j][r] + bcol[j];
        if (ACT == 1) {
          float e = v * (2.3022082f + 0.1029431f * v * v);
          float tt2 = exp2f(fminf(e, 80.0f));
          v = v * tt2 / (tt2 + 1.0f);
        }
        if (RESID == 1) v += b2f(((const u16*)resid)[(size_t)row * N + col]);
        if (RESID == 2) v += ((const float*)resid)[(size_t)row * N + col];
        if (OUTF32) ((float*)Cv)[(size_t)row * ldc + col] = v;
        else        ((u16*)Cv)[(size_t)row * ldc + col] = f2b(v);
      }
    }
  }
}

// ---------------- Flash attention: grid (B*H, S/64); qkv strided (ld=3072) ----------------
__global__ __launch_bounds__(256) void attn_k(const u16* __restrict__ QKV, const u16* __restrict__ VT,
                                              u16* __restrict__ ctx) {
  int bh = blockIdx.x;
  int b = bh >> 4;
  int q0 = blockIdx.y * 64;
  int t = threadIdx.x, wave = t >> 6, lane = t & 63, quad = lane >> 4, l16 = lane & 15;
  __shared__ u16 Ks[2][64 * 64];    // [key][d], XOR-swizzled chunks
  __shared__ u16 Vs[2][64 * 64];    // [d][key-of-tile], XOR-swizzled
  __shared__ u16 Plds[4][16][72];   // per-wave P strip (wave-private)
  const size_t base = ((size_t)b * 1024) * 3072 + (size_t)(bh & 15) * 64;
  const u16* Kbase = QKV + base + 1024;
  const u16* vtb = VT + (size_t)bh * 64 * 1024;
  int lrow = lane >> 3;                  // 0..7
  int lchunk = (lane & 7) ^ (lrow & 7);  // source-permute => phys chunk = logical ^ (row&7)
  int srow = wave * 16;                  // this wave's 16-row slab of the 64-row tile
  short8 qa[2];  // Q A-frags
  #pragma unroll
  for (int kh = 0; kh < 2; kh++)
    qa[kh] = *(const short8*)(QKV + base + (size_t)(q0 + wave * 16 + l16) * 3072 + kh * 32 + quad * 8);
  #pragma unroll
  for (int half = 0; half < 2; half++) {
    int r8 = srow + half * 8;
    gload_lds16(Kbase + (size_t)(r8 + lrow) * 3072 + lchunk * 8, &Ks[0][r8 * 64]);
    gload_lds16(vtb + (size_t)(r8 + lrow) * 1024 + lchunk * 8, &Vs[0][r8 * 64]);
  }
  f32x4 o[4] = {};
  float l_acc[4] = {0.f, 0.f, 0.f, 0.f};
  for (int c = 0; c < 16; c++) {
    int buf = c & 1;
    __syncthreads();  // drains tile-c DMA; fences buf^1 readers from iter c-1
    if (c < 15) {
      #pragma unroll
      for (int half = 0; half < 2; half++) {
        int r8 = srow + half * 8;
        gload_lds16(Kbase + (size_t)((c + 1) * 64 + r8 + lrow) * 3072 + lchunk * 8, &Ks[buf ^ 1][r8 * 64]);
        gload_lds16(vtb + (size_t)(r8 + lrow) * 1024 + (c + 1) * 64 + lchunk * 8, &Vs[buf ^ 1][r8 * 64]);
      }
    }
    f32x4 s[4] = {};
    #pragma unroll
    for (int kh = 0; kh < 2; kh++)
      #pragma unroll
      for (int j = 0; j < 4; j++) {
        int row = j * 16 + l16;
        int pc = (kh * 4 + quad) ^ (row & 7);
        short8 kb = *(const short8*)(&Ks[buf][row * 64 + pc * 8]);
        s[j] = MFMA_BF16(qa[kh], kb, s[j], 0, 0, 0);
      }
    #pragma unroll
    for (int j = 0; j < 4; j++)
      #pragma unroll
      for (int r = 0; r < 4; r++) {
        float p = exp2f(s[j][r] * 0.18033688011112042f);  // 2^(s*log2e/8)
        l_acc[r] += p;
        Plds[wave][quad * 4 + r][j * 16 + l16] = f2b(p);
      }
    #pragma unroll
    for (int kh = 0; kh < 2; kh++) {
      short8 pa = *(const short8*)(&Plds[wave][l16][kh * 32 + quad * 8]);
      #pragma unroll
      for (int d4 = 0; d4 < 4; d4++) {
        int row = d4 * 16 + l16;
        int pc = (kh * 4 + quad) ^ (row & 7);
        short8 vb = *(const short8*)(&Vs[buf][row * 64 + pc * 8]);
        o[d4] = MFMA_BF16(pa, vb, o[d4], 0, 0, 0);
      }
    }
  }
  #pragma unroll
  for (int off = 1; off < 16; off <<= 1)
    #pragma unroll
    for (int r = 0; r < 4; r++) l_acc[r] += __shfl_xor(l_acc[r], off);
  #pragma unroll
  for (int r = 0; r < 4; r++) {
    float inv = 1.0f / l_acc[r];
    size_t row = (size_t)b * 1024 + q0 + wave * 16 + quad * 4 + r;
    #pragma unroll
    for (int d4 = 0; d4 < 4; d4++) {
      int col = (bh & 15) * 64 + d4 * 16 + l16;
      ctx[row * 1024 + col] = f2b(o[d4][r] * inv);
    }
  }
}

// ---------------- launch ----------------
extern "C" void kernel_launch(void* const* d_in, const int* in_sizes, int n_in,
                              void* d_out, int out_size, void* d_ws, size_t ws_size,
                              hipStream_t stream) {
  const float* x   = (const float*)d_in[0];
  const float* Wq  = (const float*)d_in[1];  const float* bq  = (const float*)d_in[2];
  const float* Wk  = (const float*)d_in[3];  const float* bk  = (const float*)d_in[4];
  const float* Wv  = (const float*)d_in[5];  const float* bv  = (const float*)d_in[6];
  const float* Wo  = (const float*)d_in[7];  const float* bo  = (const float*)d_in[8];
  const float* W1  = (const float*)d_in[9];  const float* b1  = (const float*)d_in[10];
  const float* W2  = (const float*)d_in[11]; const float* b2  = (const float*)d_in[12];
  const float* g1  = (const float*)d_in[13]; const float* be1 = (const float*)d_in[14];
  const float* g2  = (const float*)d_in[15]; const float* be2 = (const float*)d_in[16];

  char* ws = (char*)d_ws;
  const size_t MB = 1024 * 1024;
  u16* h1    = (u16*)(ws + 0 * MB);
  u16* qkv   = (u16*)(ws + 16 * MB);
  u16* x1    = (u16*)(ws + 16 * MB);
  u16* h2    = (u16*)(ws + 32 * MB);
  u16* W2T   = (u16*)(ws + 48 * MB);
  u16* WqkvT = (u16*)(ws + 64 * MB);
  u16* WoT   = (u16*)(ws + 70 * MB);
  u16* W1T   = (u16*)(ws + 72 * MB);
  float* bqkv = (float*)(ws + 80 * MB);
  u16* h3f   = (u16*)(ws + 80 * MB);
  u16* vt    = h1;
  u16* ctx   = (u16*)d_out;
  float* out = (float*)d_out;

  transpose_k<<<dim3(32, 32), 256, 0, stream>>>(Wq, WqkvT, 1024, 1024);
  transpose_k<<<dim3(32, 32), 256, 0, stream>>>(Wk, WqkvT + (size_t)1024 * 1024, 1024, 1024);
  transpose_k<<<dim3(32, 32), 256, 0, stream>>>(Wv, WqkvT + (size_t)2048 * 1024, 1024, 1024);
  transpose_k<<<dim3(32, 32), 256, 0, stream>>>(Wo, WoT, 1024, 1024);
  transpose_k<<<dim3(128, 32), 256, 0, stream>>>(W1, W1T, 1024, 4096);
  cat3_k<<<12, 256, 0, stream>>>(bq, bk, bv, bqkv);

  ln_k<1><<<8192, 256, 0, stream>>>(x, g1, be1, h1);

  gemm256_k<0, 0, 0><<<dim3(32, 12), 512, 0, stream>>>(h1, WqkvT, bqkv, nullptr, qkv,
                                                       8192, 3072, 1024, 3072);    // fused QKV

  vtrans_k<<<dim3(64, 128), 256, 0, stream>>>(qkv, vt);                            // vt = h1 (dead)

  attn_k<<<dim3(128, 16), 256, 0, stream>>>(qkv, vt, ctx);                         // ctx = d_out[0,16M)

  gemm_k<0, 2, 0><<<dim3(64, 8), 256, 0, stream>>>(ctx, WoT, bo, x, x1,
                                                   8192, 1024, 1024, 1024);        // x1 (+fp32 x)

  transpose_k<<<dim3(32, 128), 256, 0, stream>>>(W2, W2T, 4096, 1024);             // into dead v region

  ln_k<0><<<8192, 256, 0, stream>>>(x1, g2, be2, h2);

  gemm256_k<1, 0, 0><<<dim3(32, 16), 512, 0, stream>>>(h2, W1T, b1, nullptr, h3f,
                                                       8192, 4096, 1024, 4096);    // FFN1 + GELU
  gemm_k<0, 1, 1><<<dim3(64, 8), 256, 0, stream>>>(h3f, W2T, b2, x1, out,
                                                   8192, 1024, 4096, 1024);        // FFN2 + resid

  (void)in_sizes; (void)n_in; (void)out_size; (void)ws_size;
}

// Round 7
// 515.415 us; speedup vs baseline: 1.1013x; 1.0419x over previous
//
#include <hip/hip_runtime.h>
#include <hip/hip_bf16.h>
#include <math.h>
#include <stdint.h>

typedef unsigned short u16;
typedef unsigned int u32;
typedef __attribute__((ext_vector_type(8))) short short8;   // 8 bf16 = 4 VGPRs (MFMA A/B frag)
typedef __attribute__((ext_vector_type(4))) float f32x4;    // MFMA C/D frag

__device__ __forceinline__ float b2f(u16 u) {
  union { u32 i; float f; } v; v.i = ((u32)u) << 16; return v.f;
}
__device__ __forceinline__ u16 f2b(float f) {
  union { float f; u32 i; } v; v.f = f;
  return (u16)((v.i + 0x7FFFu + ((v.i >> 16) & 1u)) >> 16);  // RNE
}

// async global->LDS DMA, 16B per lane; LDS dest = wave-uniform base + lane*16B
__device__ __forceinline__ void gload_lds16(const u16* g, u16* l) {
  __builtin_amdgcn_global_load_lds((const __attribute__((address_space(1))) void*)g,
                                   (__attribute__((address_space(3))) void*)l, 16, 0, 0);
}

#define LD8(p) (*(const short8*)(p))
#define MFMA_BF16 __builtin_amdgcn_mfma_f32_16x16x32_bf16

// ---------------- fused transpose+convert: fp32 (K x N) -> bf16 (N x K) ----------------
__global__ __launch_bounds__(256) void transpose_k(const float* __restrict__ in,
                                                   u16* __restrict__ out, int K, int N) {
  __shared__ u16 tile[32][33];
  int n0 = blockIdx.x * 32, k0 = blockIdx.y * 32;
  int tx = threadIdx.x & 31, ty = threadIdx.x >> 5;
  #pragma unroll
  for (int i = ty; i < 32; i += 8)
    tile[i][tx] = f2b(in[(size_t)(k0 + i) * N + n0 + tx]);
  __syncthreads();
  #pragma unroll
  for (int i = ty; i < 32; i += 8)
    out[(size_t)(n0 + i) * K + k0 + tx] = tile[tx][i];
}

// ---------------- concat 3 x 1024 fp32 biases ----------------
__global__ __launch_bounds__(256) void cat3_k(const float* __restrict__ a, const float* __restrict__ b,
                                              const float* __restrict__ c, float* __restrict__ o) {
  int i = blockIdx.x * 256 + threadIdx.x;
  o[i] = i < 1024 ? a[i] : (i < 2048 ? b[i - 1024] : c[i - 2048]);
}

// ---------------- per-head V transpose from strided qkv: v[s][2048+h*64+d] -> vt[(bh*64+d)][s] ----------------
__global__ __launch_bounds__(256) void vtrans_k(const u16* __restrict__ qkv, u16* __restrict__ vt) {
  __shared__ u16 tile[32][33];
  int bh = blockIdx.y, b = bh >> 4, h = bh & 15;
  int s0 = (blockIdx.x & 31) * 32, d0 = (blockIdx.x >> 5) * 32;
  int tx = threadIdx.x & 31, ty = threadIdx.x >> 5;
  #pragma unroll
  for (int i = ty; i < 32; i += 8)
    tile[i][tx] = qkv[(size_t)(b * 1024 + s0 + i) * 3072 + 2048 + h * 64 + d0 + tx];
  __syncthreads();
  #pragma unroll
  for (int i = ty; i < 32; i += 8)
    vt[(size_t)(bh * 64 + d0 + i) * 1024 + s0 + tx] = tile[tx][i];
}

// ---------------- LayerNorm over D=1024, one block per row; FP32IN: x fp32 vs bf16 ----------------
template<int FP32IN>
__global__ __launch_bounds__(256) void ln_k(const void* __restrict__ xv, const float* __restrict__ g,
                                            const float* __restrict__ be, u16* __restrict__ out) {
  int row = blockIdx.x, t = threadIdx.x;
  float f0, f1, f2, f3;
  if (FP32IN) {
    const float* xr = (const float*)xv + (size_t)row * 1024;
    float4 x4 = *(const float4*)(xr + t * 4);
    f0 = x4.x; f1 = x4.y; f2 = x4.z; f3 = x4.w;
  } else {
    const u16* xr = (const u16*)xv + (size_t)row * 1024;
    ushort4 x4 = *(const ushort4*)(xr + t * 4);
    f0 = b2f(x4.x); f1 = b2f(x4.y); f2 = b2f(x4.z); f3 = b2f(x4.w);
  }
  float s = f0 + f1 + f2 + f3;
  float ss = f0 * f0 + f1 * f1 + f2 * f2 + f3 * f3;
  #pragma unroll
  for (int off = 32; off > 0; off >>= 1) { s += __shfl_down(s, off); ss += __shfl_down(ss, off); }
  __shared__ float sb[4], ssb[4];
  if ((t & 63) == 0) { sb[t >> 6] = s; ssb[t >> 6] = ss; }
  __syncthreads();
  s = sb[0] + sb[1] + sb[2] + sb[3];
  ss = ssb[0] + ssb[1] + ssb[2] + ssb[3];
  float mu = s * (1.0f / 1024.0f);
  float var = ss * (1.0f / 1024.0f) - mu * mu;
  float rstd = rsqrtf(var + 1e-5f);
  float4 gv = *(const float4*)(g + t * 4);
  float4 bv = *(const float4*)(be + t * 4);
  ushort4 o;
  o.x = f2b((f0 - mu) * rstd * gv.x + bv.x);
  o.y = f2b((f1 - mu) * rstd * gv.y + bv.y);
  o.z = f2b((f2 - mu) * rstd * gv.z + bv.z);
  o.w = f2b((f3 - mu) * rstd * gv.w + bv.w);
  *(ushort4*)(out + (size_t)row * 1024 + t * 4) = o;
}

// ======================= gemm256_k: BK=64 4-phase schedule (r6 proven; QKV + FFN1) =============
// BM=BN=256, BK=64, 8 waves (2M x 4N), per-wave 128x64 (acc[8][4]). 2 LDS buffers (128KB).
// See r5/r6 notes: P0/P1 stage A/B of tile tt+1; P2/P3 pure compute; boundary vmcnt(0) whose
// waited loads were issued >=2 phases earlier. Swizzle: 128B row pitch, chunk XOR (row&7).
template<int ACT, int RESID, int OUTF32>
__global__ __launch_bounds__(512, 2) void gemm256_k(const u16* __restrict__ A, const u16* __restrict__ Bt,
                                                    const float* __restrict__ bias, const void* __restrict__ resid,
                                                    void* __restrict__ Cv, int M, int N, int K, int ldc) {
  __shared__ u16 As[2][256 * 64];   // 2 x 32KB
  __shared__ u16 Bs[2][256 * 64];   // 2 x 32KB
  int Ny = N >> 8;
  int lin = blockIdx.y * 32 + blockIdx.x;
  int c8 = lin & 7, sblk = lin >> 3;
  int mq = sblk / Ny;
  int m0 = ((mq << 3) | c8) << 8;
  int n0 = (sblk - mq * Ny) << 8;
  int t = threadIdx.x;
  int wave = t >> 6, lane = t & 63, quad = lane >> 4, l16 = lane & 15;
  int wm = (wave >> 2) << 7;            // 0 | 128
  int wn = (wave & 3) << 6;             // 0..192
  f32x4 acc[8][4] = {};
  int lrow = lane >> 3;                        // 0..7
  int lchunk = (lane & 7) ^ lrow;              // src chunk = logical ^ (row&7)
  const u16* Ab = A + (size_t)(m0 + wave * 32 + lrow) * K + lchunk * 8;
  const u16* Bb = Bt + (size_t)(n0 + wave * 32 + lrow) * K + lchunk * 8;
  const int sbase = wave * 32 * 64;            // wave's staging slab base (elements); +g*8*64
  const int x7 = l16 & 7;
  const int rdA = (wm + l16) * 64;             // + i*1024 + cswz
  const int rdB = (wn + l16) * 64;             // + j*1024 + cswz
  const int cz0 = (quad ^ x7) * 8;             // kk=0: logical chunk = quad
  const int cz1 = ((4 + quad) ^ x7) * 8;       // kk=1: logical chunk = 4+quad
  const int niter = K >> 6;
  // ---- prologue: stage tile 0 into buf0 (8 gloads/wave) ----
  #pragma unroll
  for (int g = 0; g < 4; g++) {
    gload_lds16(Ab + (size_t)g * 8 * K, &As[0][sbase + g * 8 * 64]);
    gload_lds16(Bb + (size_t)g * 8 * K, &Bs[0][sbase + g * 8 * 64]);
  }
  asm volatile("s_waitcnt vmcnt(0)" ::: "memory");
  __builtin_amdgcn_s_barrier();
  __builtin_amdgcn_sched_barrier(0);
  for (int tt = 0; tt < niter; tt++) {
    int buf = tt & 1;
    const bool pf = (tt + 1 < niter);
    const int kpf = (tt + 1) << 6;
    const u16* Ac = &As[buf][0];
    const u16* Bc = &Bs[buf][0];
    u16* Aw = &As[buf ^ 1][0];
    u16* Bw = &Bs[buf ^ 1][0];
    short8 a0, a1, a2, a3, a4, a5, a6, a7, b0, b1, b2, b3;
    // ---------- P0: kk=0 i0-3 + all b ; stage A(tile tt+1) ----------
    a0 = LD8(Ac + rdA + cz0);
    a1 = LD8(Ac + rdA + 1024 + cz0);
    a2 = LD8(Ac + rdA + 2048 + cz0);
    a3 = LD8(Ac + rdA + 3072 + cz0);
    b0 = LD8(Bc + rdB + cz0);
    b1 = LD8(Bc + rdB + 1024 + cz0);
    b2 = LD8(Bc + rdB + 2048 + cz0);
    b3 = LD8(Bc + rdB + 3072 + cz0);
    if (pf) {
      #pragma unroll
      for (int g = 0; g < 4; g++)
        gload_lds16(Ab + kpf + (size_t)g * 8 * K, Aw + sbase + g * 8 * 64);
    }
    __builtin_amdgcn_s_barrier();
    asm volatile("s_waitcnt lgkmcnt(0)" ::: "memory");
    __builtin_amdgcn_sched_barrier(0);
    __builtin_amdgcn_s_setprio(1);
    acc[0][0] = MFMA_BF16(a0, b0, acc[0][0], 0, 0, 0);
    acc[0][1] = MFMA_BF16(a0, b1, acc[0][1], 0, 0, 0);
    acc[0][2] = MFMA_BF16(a0, b2, acc[0][2], 0, 0, 0);
    acc[0][3] = MFMA_BF16(a0, b3, acc[0][3], 0, 0, 0);
    acc[1][0] = MFMA_BF16(a1, b0, acc[1][0], 0, 0, 0);
    acc[1][1] = MFMA_BF16(a1, b1, acc[1][1], 0, 0, 0);
    acc[1][2] = MFMA_BF16(a1, b2, acc[1][2], 0, 0, 0);
    acc[1][3] = MFMA_BF16(a1, b3, acc[1][3], 0, 0, 0);
    acc[2][0] = MFMA_BF16(a2, b0, acc[2][0], 0, 0, 0);
    acc[2][1] = MFMA_BF16(a2, b1, acc[2][1], 0, 0, 0);
    acc[2][2] = MFMA_BF16(a2, b2, acc[2][2], 0, 0, 0);
    acc[2][3] = MFMA_BF16(a2, b3, acc[2][3], 0, 0, 0);
    acc[3][0] = MFMA_BF16(a3, b0, acc[3][0], 0, 0, 0);
    acc[3][1] = MFMA_BF16(a3, b1, acc[3][1], 0, 0, 0);
    acc[3][2] = MFMA_BF16(a3, b2, acc[3][2], 0, 0, 0);
    acc[3][3] = MFMA_BF16(a3, b3, acc[3][3], 0, 0, 0);
    __builtin_amdgcn_s_setprio(0);
    __builtin_amdgcn_s_barrier();
    __builtin_amdgcn_sched_barrier(0);
    // ---------- P1: kk=0 i4-7 ; stage B(tile tt+1) ----------
    a4 = LD8(Ac + rdA + 4096 + cz0);
    a5 = LD8(Ac + rdA + 5120 + cz0);
    a6 = LD8(Ac + rdA + 6144 + cz0);
    a7 = LD8(Ac + rdA + 7168 + cz0);
    if (pf) {
      #pragma unroll
      for (int g = 0; g < 4; g++)
        gload_lds16(Bb + kpf + (size_t)g * 8 * K, Bw + sbase + g * 8 * 64);
    }
    __builtin_amdgcn_s_barrier();
    asm volatile("s_waitcnt lgkmcnt(0)" ::: "memory");
    __builtin_amdgcn_sched_barrier(0);
    __builtin_amdgcn_s_setprio(1);
    acc[4][0] = MFMA_BF16(a4, b0, acc[4][0], 0, 0, 0);
    acc[4][1] = MFMA_BF16(a4, b1, acc[4][1], 0, 0, 0);
    acc[4][2] = MFMA_BF16(a4, b2, acc[4][2], 0, 0, 0);
    acc[4][3] = MFMA_BF16(a4, b3, acc[4][3], 0, 0, 0);
    acc[5][0] = MFMA_BF16(a5, b0, acc[5][0], 0, 0, 0);
    acc[5][1] = MFMA_BF16(a5, b1, acc[5][1], 0, 0, 0);
    acc[5][2] = MFMA_BF16(a5, b2, acc[5][2], 0, 0, 0);
    acc[5][3] = MFMA_BF16(a5, b3, acc[5][3], 0, 0, 0);
    acc[6][0] = MFMA_BF16(a6, b0, acc[6][0], 0, 0, 0);
    acc[6][1] = MFMA_BF16(a6, b1, acc[6][1], 0, 0, 0);
    acc[6][2] = MFMA_BF16(a6, b2, acc[6][2], 0, 0, 0);
    acc[6][3] = MFMA_BF16(a6, b3, acc[6][3], 0, 0, 0);
    acc[7][0] = MFMA_BF16(a7, b0, acc[7][0], 0, 0, 0);
    acc[7][1] = MFMA_BF16(a7, b1, acc[7][1], 0, 0, 0);
    acc[7][2] = MFMA_BF16(a7, b2, acc[7][2], 0, 0, 0);
    acc[7][3] = MFMA_BF16(a7, b3, acc[7][3], 0, 0, 0);
    __builtin_amdgcn_s_setprio(0);
    __builtin_amdgcn_s_barrier();
    __builtin_amdgcn_sched_barrier(0);
    // ---------- P2: kk=1 i0-3 + all b ----------
    a0 = LD8(Ac + rdA + cz1);
    a1 = LD8(Ac + rdA + 1024 + cz1);
    a2 = LD8(Ac + rdA + 2048 + cz1);
    a3 = LD8(Ac + rdA + 3072 + cz1);
    b0 = LD8(Bc + rdB + cz1);
    b1 = LD8(Bc + rdB + 1024 + cz1);
    b2 = LD8(Bc + rdB + 2048 + cz1);
    b3 = LD8(Bc + rdB + 3072 + cz1);
    __builtin_amdgcn_s_barrier();
    asm volatile("s_waitcnt lgkmcnt(0)" ::: "memory");
    __builtin_amdgcn_sched_barrier(0);
    __builtin_amdgcn_s_setprio(1);
    acc[0][0] = MFMA_BF16(a0, b0, acc[0][0], 0, 0, 0);
    acc[0][1] = MFMA_BF16(a0, b1, acc[0][1], 0, 0, 0);
    acc[0][2] = MFMA_BF16(a0, b2, acc[0][2], 0, 0, 0);
    acc[0][3] = MFMA_BF16(a0, b3, acc[0][3], 0, 0, 0);
    acc[1][0] = MFMA_BF16(a1, b0, acc[1][0], 0, 0, 0);
    acc[1][1] = MFMA_BF16(a1, b1, acc[1][1], 0, 0, 0);
    acc[1][2] = MFMA_BF16(a1, b2, acc[1][2], 0, 0, 0);
    acc[1][3] = MFMA_BF16(a1, b3, acc[1][3], 0, 0, 0);
    acc[2][0] = MFMA_BF16(a2, b0, acc[2][0], 0, 0, 0);
    acc[2][1] = MFMA_BF16(a2, b1, acc[2][1], 0, 0, 0);
    acc[2][2] = MFMA_BF16(a2, b2, acc[2][2], 0, 0, 0);
    acc[2][3] = MFMA_BF16(a2, b3, acc[2][3], 0, 0, 0);
    acc[3][0] = MFMA_BF16(a3, b0, acc[3][0], 0, 0, 0);
    acc[3][1] = MFMA_BF16(a3, b1, acc[3][1], 0, 0, 0);
    acc[3][2] = MFMA_BF16(a3, b2, acc[3][2], 0, 0, 0);
    acc[3][3] = MFMA_BF16(a3, b3, acc[3][3], 0, 0, 0);
    __builtin_amdgcn_s_setprio(0);
    __builtin_amdgcn_s_barrier();
    __builtin_amdgcn_sched_barrier(0);
    // ---------- P3: kk=1 i4-7 ; K-tile boundary ----------
    a4 = LD8(Ac + rdA + 4096 + cz1);
    a5 = LD8(Ac + rdA + 5120 + cz1);
    a6 = LD8(Ac + rdA + 6144 + cz1);
    a7 = LD8(Ac + rdA + 7168 + cz1);
    __builtin_amdgcn_s_barrier();
    asm volatile("s_waitcnt lgkmcnt(0)" ::: "memory");
    __builtin_amdgcn_sched_barrier(0);
    __builtin_amdgcn_s_setprio(1);
    acc[4][0] = MFMA_BF16(a4, b0, acc[4][0], 0, 0, 0);
    acc[4][1] = MFMA_BF16(a4, b1, acc[4][1], 0, 0, 0);
    acc[4][2] = MFMA_BF16(a4, b2, acc[4][2], 0, 0, 0);
    acc[4][3] = MFMA_BF16(a4, b3, acc[4][3], 0, 0, 0);
    acc[5][0] = MFMA_BF16(a5, b0, acc[5][0], 0, 0, 0);
    acc[5][1] = MFMA_BF16(a5, b1, acc[5][1], 0, 0, 0);
    acc[5][2] = MFMA_BF16(a5, b2, acc[5][2], 0, 0, 0);
    acc[5][3] = MFMA_BF16(a5, b3, acc[5][3], 0, 0, 0);
    acc[6][0] = MFMA_BF16(a6, b0, acc[6][0], 0, 0, 0);
    acc[6][1] = MFMA_BF16(a6, b1, acc[6][1], 0, 0, 0);
    acc[6][2] = MFMA_BF16(a6, b2, acc[6][2], 0, 0, 0);
    acc[6][3] = MFMA_BF16(a6, b3, acc[6][3], 0, 0, 0);
    acc[7][0] = MFMA_BF16(a7, b0, acc[7][0], 0, 0, 0);
    acc[7][1] = MFMA_BF16(a7, b1, acc[7][1], 0, 0, 0);
    acc[7][2] = MFMA_BF16(a7, b2, acc[7][2], 0, 0, 0);
    acc[7][3] = MFMA_BF16(a7, b3, acc[7][3], 0, 0, 0);
    __builtin_amdgcn_s_setprio(0);
    if (pf) {
      asm volatile("s_waitcnt vmcnt(0)" ::: "memory");  // loads issued >=2 phases ago
      __builtin_amdgcn_s_barrier();
      __builtin_amdgcn_sched_barrier(0);
    }
  }
  // epilogue: C/D layout col=lane&15, row=quad*4+reg
  float bcol[4];
  #pragma unroll
  for (int j = 0; j < 4; j++) bcol[j] = bias[n0 + wn + j * 16 + l16];
  #pragma unroll
  for (int i = 0; i < 8; i++) {
    #pragma unroll
    for (int r = 0; r < 4; r++) {
      int row = m0 + wm + i * 16 + quad * 4 + r;
      #pragma unroll
      for (int j = 0; j < 4; j++) {
        int col = n0 + wn + j * 16 + l16;
        float v = acc[i][j][r] + bcol[j];
        if (ACT == 1) {
          float e = v * (2.3022082f + 0.1029431f * v * v);
          float tt2 = exp2f(fminf(e, 80.0f));
          v = v * tt2 / (tt2 + 1.0f);
        }
        if (RESID == 1) v += b2f(((const u16*)resid)[(size_t)row * N + col]);
        if (RESID == 2) v += ((const float*)resid)[(size_t)row * N + col];
        if (OUTF32) ((float*)Cv)[(size_t)row * ldc + col] = v;
        else        ((u16*)Cv)[(size_t)row * ldc + col] = f2b(v);
      }
    }
  }
}

// ======================= gemm256n_k: BM=256 BN=128, 3-buf, counted vmcnt (O-proj + FFN2) =======
// Grid dim3(32, N/128) = 256 blocks (N=1024) = 1 block/CU. 8 waves as 4M x 2N, per-wave 64x64
// (acc[4][4]). LDS: 3 buf x (A 32KB + B 16KB) = 144KB. Prefetch depth 2 K-tiles (6 gloads/tile:
// A=4, B=2); boundary s_waitcnt vmcnt(6) -> tile tt+1's 6 loads landed, tt+2's 6 in flight
// (issued a full tile ~600cy earlier). Never drains to 0 until tail (T4 on phase-split, the
// combination r6 validated; r2's failure was counted-vmcnt on the UNSPLIT 2-phase loop).
// Per K-tile: P0 {8 ds_read kk0 || stage A(tt+2) -> bar -> lgkm0 -> 16 MFMA},
//             P1 {8 ds_read kk1 || stage B(tt+2) -> bar -> lgkm0 -> 16 MFMA}, boundary.
// WAR-safe: buf (tt+2)%3 was read at tile tt-1, retired at tt-1's P1 lgkm0 before the boundary
// barrier; writes issue after it. Per-wave vmcnt precedes the shared barrier (cross-wave).
// Swizzle: 128B row pitch -> chunk XOR (row&7) (0 conflicts measured, r3/r5 pattern).
template<int ACT, int RESID, int OUTF32>
__global__ __launch_bounds__(512, 2) void gemm256n_k(const u16* __restrict__ A, const u16* __restrict__ Bt,
                                                     const float* __restrict__ bias, const void* __restrict__ resid,
                                                     void* __restrict__ Cv, int M, int N, int K, int ldc) {
  __shared__ u16 As[3][256 * 64];   // 3 x 32KB
  __shared__ u16 Bs[3][128 * 64];   // 3 x 16KB
  int Ny = N >> 7;
  int lin = blockIdx.y * 32 + blockIdx.x;
  int c8 = lin & 7, sblk = lin >> 3;
  int mq = sblk / Ny;
  int m0 = ((mq << 3) | c8) << 8;
  int n0 = (sblk - mq * Ny) << 7;
  int t = threadIdx.x;
  int wave = t >> 6, lane = t & 63, quad = lane >> 4, l16 = lane & 15;
  int wm = (wave >> 1) << 6;            // 0 | 64 | 128 | 192
  int wn = (wave & 1) << 6;             // 0 | 64
  f32x4 acc[4][4] = {};
  int lrow = lane >> 3;                        // 0..7
  int lchunk = (lane & 7) ^ lrow;              // src chunk = logical ^ (row&7)
  const u16* Ab = A + (size_t)(m0 + wave * 32 + lrow) * K + lchunk * 8;
  const u16* Bb = Bt + (size_t)(n0 + wave * 16 + lrow) * K + lchunk * 8;
  const int sbA = wave * 32 * 64;              // A staging slab (4 instrs x 8 rows)
  const int sbB = wave * 16 * 64;              // B staging slab (2 instrs x 8 rows)
  const int x7 = l16 & 7;
  const int rdA = (wm + l16) * 64;             // + i*1024 + cz
  const int rdB = (wn + l16) * 64;             // + j*1024 + cz
  const int cz0 = (quad ^ x7) * 8;
  const int cz1 = ((4 + quad) ^ x7) * 8;
  const int niter = K >> 6;
  // ---- prologue: stage tiles 0,1 (12 gloads/wave) ----
  #pragma unroll
  for (int p = 0; p < 2; p++) {
    #pragma unroll
    for (int g = 0; g < 4; g++)
      gload_lds16(Ab + (p << 6) + (size_t)g * 8 * K, &As[p][sbA + g * 8 * 64]);
    #pragma unroll
    for (int g = 0; g < 2; g++)
      gload_lds16(Bb + (p << 6) + (size_t)g * 8 * K, &Bs[p][sbB + g * 8 * 64]);
  }
  asm volatile("s_waitcnt vmcnt(6)" ::: "memory");   // tile0 landed; tile1 in flight
  __builtin_amdgcn_s_barrier();
  __builtin_amdgcn_sched_barrier(0);
  int cur = 0;
  for (int tt = 0; tt < niter; tt++) {
    int wb = cur + 2; if (wb >= 3) wb -= 3;
    const bool pf = (tt + 2 < niter);
    const int kpf = (tt + 2) << 6;
    const u16* Ac = &As[cur][0];
    const u16* Bc = &Bs[cur][0];
    short8 a0, a1, a2, a3, b0, b1, b2, b3;
    // ---------- P0: kk=0 (a0-3, b0-3) ; stage A(tile tt+2) ----------
    a0 = LD8(Ac + rdA + cz0);
    a1 = LD8(Ac + rdA + 1024 + cz0);
    a2 = LD8(Ac + rdA + 2048 + cz0);
    a3 = LD8(Ac + rdA + 3072 + cz0);
    b0 = LD8(Bc + rdB + cz0);
    b1 = LD8(Bc + rdB + 1024 + cz0);
    b2 = LD8(Bc + rdB + 2048 + cz0);
    b3 = LD8(Bc + rdB + 3072 + cz0);
    if (pf) {
      #pragma unroll
      for (int g = 0; g < 4; g++)
        gload_lds16(Ab + kpf + (size_t)g * 8 * K, &As[wb][sbA + g * 8 * 64]);
    }
    __builtin_amdgcn_s_barrier();
    asm volatile("s_waitcnt lgkmcnt(0)" ::: "memory");
    __builtin_amdgcn_sched_barrier(0);
    __builtin_amdgcn_s_setprio(1);
    acc[0][0] = MFMA_BF16(a0, b0, acc[0][0], 0, 0, 0);
    acc[0][1] = MFMA_BF16(a0, b1, acc[0][1], 0, 0, 0);
    acc[0][2] = MFMA_BF16(a0, b2, acc[0][2], 0, 0, 0);
    acc[0][3] = MFMA_BF16(a0, b3, acc[0][3], 0, 0, 0);
    acc[1][0] = MFMA_BF16(a1, b0, acc[1][0], 0, 0, 0);
    acc[1][1] = MFMA_BF16(a1, b1, acc[1][1], 0, 0, 0);
    acc[1][2] = MFMA_BF16(a1, b2, acc[1][2], 0, 0, 0);
    acc[1][3] = MFMA_BF16(a1, b3, acc[1][3], 0, 0, 0);
    acc[2][0] = MFMA_BF16(a2, b0, acc[2][0], 0, 0, 0);
    acc[2][1] = MFMA_BF16(a2, b1, acc[2][1], 0, 0, 0);
    acc[2][2] = MFMA_BF16(a2, b2, acc[2][2], 0, 0, 0);
    acc[2][3] = MFMA_BF16(a2, b3, acc[2][3], 0, 0, 0);
    acc[3][0] = MFMA_BF16(a3, b0, acc[3][0], 0, 0, 0);
    acc[3][1] = MFMA_BF16(a3, b1, acc[3][1], 0, 0, 0);
    acc[3][2] = MFMA_BF16(a3, b2, acc[3][2], 0, 0, 0);
    acc[3][3] = MFMA_BF16(a3, b3, acc[3][3], 0, 0, 0);
    __builtin_amdgcn_s_setprio(0);
    __builtin_amdgcn_s_barrier();
    __builtin_amdgcn_sched_barrier(0);
    // ---------- P1: kk=1 (a,b re-read) ; stage B(tile tt+2) ----------
    a0 = LD8(Ac + rdA + cz1);
    a1 = LD8(Ac + rdA + 1024 + cz1);
    a2 = LD8(Ac + rdA + 2048 + cz1);
    a3 = LD8(Ac + rdA + 3072 + cz1);
    b0 = LD8(Bc + rdB + cz1);
    b1 = LD8(Bc + rdB + 1024 + cz1);
    b2 = LD8(Bc + rdB + 2048 + cz1);
    b3 = LD8(Bc + rdB + 3072 + cz1);
    if (pf) {
      #pragma unroll
      for (int g = 0; g < 2; g++)
        gload_lds16(Bb + kpf + (size_t)g * 8 * K, &Bs[wb][sbB + g * 8 * 64]);
    }
    __builtin_amdgcn_s_barrier();
    asm volatile("s_waitcnt lgkmcnt(0)" ::: "memory");
    __builtin_amdgcn_sched_barrier(0);
    __builtin_amdgcn_s_setprio(1);
    acc[0][0] = MFMA_BF16(a0, b0, acc[0][0], 0, 0, 0);
    acc[0][1] = MFMA_BF16(a0, b1, acc[0][1], 0, 0, 0);
    acc[0][2] = MFMA_BF16(a0, b2, acc[0][2], 0, 0, 0);
    acc[0][3] = MFMA_BF16(a0, b3, acc[0][3], 0, 0, 0);
    acc[1][0] = MFMA_BF16(a1, b0, acc[1][0], 0, 0, 0);
    acc[1][1] = MFMA_BF16(a1, b1, acc[1][1], 0, 0, 0);
    acc[1][2] = MFMA_BF16(a1, b2, acc[1][2], 0, 0, 0);
    acc[1][3] = MFMA_BF16(a1, b3, acc[1][3], 0, 0, 0);
    acc[2][0] = MFMA_BF16(a2, b0, acc[2][0], 0, 0, 0);
    acc[2][1] = MFMA_BF16(a2, b1, acc[2][1], 0, 0, 0);
    acc[2][2] = MFMA_BF16(a2, b2, acc[2][2], 0, 0, 0);
    acc[2][3] = MFMA_BF16(a2, b3, acc[2][3], 0, 0, 0);
    acc[3][0] = MFMA_BF16(a3, b0, acc[3][0], 0, 0, 0);
    acc[3][1] = MFMA_BF16(a3, b1, acc[3][1], 0, 0, 0);
    acc[3][2] = MFMA_BF16(a3, b2, acc[3][2], 0, 0, 0);
    acc[3][3] = MFMA_BF16(a3, b3, acc[3][3], 0, 0, 0);
    __builtin_amdgcn_s_setprio(0);
    if (tt + 2 < niter) {
      asm volatile("s_waitcnt vmcnt(6)" ::: "memory");  // tile tt+1 landed; tt+2 in flight
    } else if (tt + 1 < niter) {
      asm volatile("s_waitcnt vmcnt(0)" ::: "memory");  // tail drain
    }
    if (tt + 1 < niter) {
      __builtin_amdgcn_s_barrier();
      __builtin_amdgcn_sched_barrier(0);
    }
    cur = (cur == 2) ? 0 : cur + 1;
  }
  // epilogue: C/D layout col=lane&15, row=quad*4+reg
  float bcol[4];
  #pragma unroll
  for (int j = 0; j < 4; j++) bcol[j] = bias[n0 + wn + j * 16 + l16];
  #pragma unroll
  for (int i = 0; i < 4; i++) {
    #pragma unroll
    for (int r = 0; r < 4; r++) {
      int row = m0 + wm + i * 16 + quad * 4 + r;
      #pragma unroll
      for (int j = 0; j < 4; j++) {
        int col = n0 + wn + j * 16 + l16;
        float v = acc[i][j][r] + bcol[j];
        if (ACT == 1) {
          float e = v * (2.3022082f + 0.1029431f * v * v);
          float tt2 = exp2f(fminf(e, 80.0f));
          v = v * tt2 / (tt2 + 1.0f);
        }
        if (RESID == 1) v += b2f(((const u16*)resid)[(size_t)row * N + col]);
        if (RESID == 2) v += ((const float*)resid)[(size_t)row * N + col];
        if (OUTF32) ((float*)Cv)[(size_t)row * ldc + col] = v;
        else        ((u16*)Cv)[(size_t)row * ldc + col] = f2b(v);
      }
    }
  }
}

// ---------------- Flash attention: grid (B*H, S/64); qkv strided (ld=3072) ----------------
__global__ __launch_bounds__(256) void attn_k(const u16* __restrict__ QKV, const u16* __restrict__ VT,
                                              u16* __restrict__ ctx) {
  int bh = blockIdx.x;
  int b = bh >> 4;
  int q0 = blockIdx.y * 64;
  int t = threadIdx.x, wave = t >> 6, lane = t & 63, quad = lane >> 4, l16 = lane & 15;
  __shared__ u16 Ks[2][64 * 64];    // [key][d], XOR-swizzled chunks
  __shared__ u16 Vs[2][64 * 64];    // [d][key-of-tile], XOR-swizzled
  __shared__ u16 Plds[4][16][72];   // per-wave P strip (wave-private)
  const size_t base = ((size_t)b * 1024) * 3072 + (size_t)(bh & 15) * 64;
  const u16* Kbase = QKV + base + 1024;
  const u16* vtb = VT + (size_t)bh * 64 * 1024;
  int lrow = lane >> 3;                  // 0..7
  int lchunk = (lane & 7) ^ (lrow & 7);  // source-permute => phys chunk = logical ^ (row&7)
  int srow = wave * 16;                  // this wave's 16-row slab of the 64-row tile
  short8 qa[2];  // Q A-frags
  #pragma unroll
  for (int kh = 0; kh < 2; kh++)
    qa[kh] = *(const short8*)(QKV + base + (size_t)(q0 + wave * 16 + l16) * 3072 + kh * 32 + quad * 8);
  #pragma unroll
  for (int half = 0; half < 2; half++) {
    int r8 = srow + half * 8;
    gload_lds16(Kbase + (size_t)(r8 + lrow) * 3072 + lchunk * 8, &Ks[0][r8 * 64]);
    gload_lds16(vtb + (size_t)(r8 + lrow) * 1024 + lchunk * 8, &Vs[0][r8 * 64]);
  }
  f32x4 o[4] = {};
  float l_acc[4] = {0.f, 0.f, 0.f, 0.f};
  for (int c = 0; c < 16; c++) {
    int buf = c & 1;
    __syncthreads();  // drains tile-c DMA; fences buf^1 readers from iter c-1
    if (c < 15) {
      #pragma unroll
      for (int half = 0; half < 2; half++) {
        int r8 = srow + half * 8;
        gload_lds16(Kbase + (size_t)((c + 1) * 64 + r8 + lrow) * 3072 + lchunk * 8, &Ks[buf ^ 1][r8 * 64]);
        gload_lds16(vtb + (size_t)(r8 + lrow) * 1024 + (c + 1) * 64 + lchunk * 8, &Vs[buf ^ 1][r8 * 64]);
      }
    }
    f32x4 s[4] = {};
    #pragma unroll
    for (int kh = 0; kh < 2; kh++)
      #pragma unroll
      for (int j = 0; j < 4; j++) {
        int row = j * 16 + l16;
        int pc = (kh * 4 + quad) ^ (row & 7);
        short8 kb = *(const short8*)(&Ks[buf][row * 64 + pc * 8]);
        s[j] = MFMA_BF16(qa[kh], kb, s[j], 0, 0, 0);
      }
    #pragma unroll
    for (int j = 0; j < 4; j++)
      #pragma unroll
      for (int r = 0; r < 4; r++) {
        float p = exp2f(s[j][r] * 0.18033688011112042f);  // 2^(s*log2e/8)
        l_acc[r] += p;
        Plds[wave][quad * 4 + r][j * 16 + l16] = f2b(p);
      }
    #pragma unroll
    for (int kh = 0; kh < 2; kh++) {
      short8 pa = *(const short8*)(&Plds[wave][l16][kh * 32 + quad * 8]);
      #pragma unroll
      for (int d4 = 0; d4 < 4; d4++) {
        int row = d4 * 16 + l16;
        int pc = (kh * 4 + quad) ^ (row & 7);
        short8 vb = *(const short8*)(&Vs[buf][row * 64 + pc * 8]);
        o[d4] = MFMA_BF16(pa, vb, o[d4], 0, 0, 0);
      }
    }
  }
  #pragma unroll
  for (int off = 1; off < 16; off <<= 1)
    #pragma unroll
    for (int r = 0; r < 4; r++) l_acc[r] += __shfl_xor(l_acc[r], off);
  #pragma unroll
  for (int r = 0; r < 4; r++) {
    float inv = 1.0f / l_acc[r];
    size_t row = (size_t)b * 1024 + q0 + wave * 16 + quad * 4 + r;
    #pragma unroll
    for (int d4 = 0; d4 < 4; d4++) {
      int col = (bh & 15) * 64 + d4 * 16 + l16;
      ctx[row * 1024 + col] = f2b(o[d4][r] * inv);
    }
  }
}

// ---------------- launch ----------------
extern "C" void kernel_launch(void* const* d_in, const int* in_sizes, int n_in,
                              void* d_out, int out_size, void* d_ws, size_t ws_size,
                              hipStream_t stream) {
  const float* x   = (const float*)d_in[0];
  const float* Wq  = (const float*)d_in[1];  const float* bq  = (const float*)d_in[2];
  const float* Wk  = (const float*)d_in[3];  const float* bk  = (const float*)d_in[4];
  const float* Wv  = (const float*)d_in[5];  const float* bv  = (const float*)d_in[6];
  const float* Wo  = (const float*)d_in[7];  const float* bo  = (const float*)d_in[8];
  const float* W1  = (const float*)d_in[9];  const float* b1  = (const float*)d_in[10];
  const float* W2  = (const float*)d_in[11]; const float* b2  = (const float*)d_in[12];
  const float* g1  = (const float*)d_in[13]; const float* be1 = (const float*)d_in[14];
  const float* g2  = (const float*)d_in[15]; const float* be2 = (const float*)d_in[16];

  char* ws = (char*)d_ws;
  const size_t MB = 1024 * 1024;
  u16* h1    = (u16*)(ws + 0 * MB);
  u16* qkv   = (u16*)(ws + 16 * MB);
  u16* x1    = (u16*)(ws + 16 * MB);
  u16* h2    = (u16*)(ws + 32 * MB);
  u16* W2T   = (u16*)(ws + 48 * MB);
  u16* WqkvT = (u16*)(ws + 64 * MB);
  u16* WoT   = (u16*)(ws + 70 * MB);
  u16* W1T   = (u16*)(ws + 72 * MB);
  float* bqkv = (float*)(ws + 80 * MB);
  u16* h3f   = (u16*)(ws + 80 * MB);
  u16* vt    = h1;
  u16* ctx   = (u16*)d_out;
  float* out = (float*)d_out;

  transpose_k<<<dim3(32, 32), 256, 0, stream>>>(Wq, WqkvT, 1024, 1024);
  transpose_k<<<dim3(32, 32), 256, 0, stream>>>(Wk, WqkvT + (size_t)1024 * 1024, 1024, 1024);
  transpose_k<<<dim3(32, 32), 256, 0, stream>>>(Wv, WqkvT + (size_t)2048 * 1024, 1024, 1024);
  transpose_k<<<dim3(32, 32), 256, 0, stream>>>(Wo, WoT, 1024, 1024);
  transpose_k<<<dim3(128, 32), 256, 0, stream>>>(W1, W1T, 1024, 4096);
  cat3_k<<<12, 256, 0, stream>>>(bq, bk, bv, bqkv);

  ln_k<1><<<8192, 256, 0, stream>>>(x, g1, be1, h1);

  gemm256_k<0, 0, 0><<<dim3(32, 12), 512, 0, stream>>>(h1, WqkvT, bqkv, nullptr, qkv,
                                                       8192, 3072, 1024, 3072);    // fused QKV

  vtrans_k<<<dim3(64, 128), 256, 0, stream>>>(qkv, vt);                            // vt = h1 (dead)

  attn_k<<<dim3(128, 16), 256, 0, stream>>>(qkv, vt, ctx);                         // ctx = d_out[0,16M)

  gemm256n_k<0, 2, 0><<<dim3(32, 8), 512, 0, stream>>>(ctx, WoT, bo, x, x1,
                                                       8192, 1024, 1024, 1024);    // x1 (+fp32 x)

  transpose_k<<<dim3(32, 128), 256, 0, stream>>>(W2, W2T, 4096, 1024);             // into dead v region

  ln_k<0><<<8192, 256, 0, stream>>>(x1, g2, be2, h2);

  gemm256_k<1, 0, 0><<<dim3(32, 16), 512, 0, stream>>>(h2, W1T, b1, nullptr, h3f,
                                                       8192, 4096, 1024, 4096);    // FFN1 + GELU
  gemm256n_k<0, 1, 1><<<dim3(32, 8), 512, 0, stream>>>(h3f, W2T, b2, x1, out,
                                                       8192, 1024, 4096, 1024);    // FFN2 + resid

  (void)in_sizes; (void)n_in; (void)out_size; (void)ws_size;
}